// Round 3
// baseline (504.798 us; speedup 1.0000x reference)
//
#include <hip/hip_runtime.h>

#define H 64
#define EPB 4096        // edges per bin block (489 blocks)
#define BMAX 400        // >= bucket count (391)
#define ST 256          // taxon rows per bucket
#define SP 512          // palmprint rows per bucket
#define LSHT 18         // t-entry: (dst&255)<<18 | src
#define LSHP 17         // p-entry: (src&511)<<17 | dst
#define CAPB 5632       // bucket capacity (mean 5120 + 7 sigma); %4==0

typedef _Float16 half2v __attribute__((ext_vector_type(2)));
typedef _Float16 half8v __attribute__((ext_vector_type(8)));
typedef _Float16 f16x8  __attribute__((ext_vector_type(8)));
typedef float    f32x4  __attribute__((ext_vector_type(4)));
typedef int      i32x4  __attribute__((ext_vector_type(4)));

#if defined(__has_builtin)
#if __has_builtin(__builtin_amdgcn_fdot2)
#define HAS_FDOT2 1
#endif
#endif

#define MFMA16(a, b, c) __builtin_amdgcn_mfma_f32_16x16x32_f16(a, b, c, 0, 0, 0)

// ---- MFMA dual GEMM device body: C1 = A@W1, C2 = A@W2 + b2 (f16 out) ----
template <int HALF_IN>
__device__ __forceinline__ void mfma_dual_dev(const void* __restrict__ Av,
                                              const float* __restrict__ W1,
                                              const float* __restrict__ W2,
                                              const float* __restrict__ b2,
                                              _Float16* __restrict__ C1,
                                              _Float16* __restrict__ C2,
                                              int N, int wid, int nwaves) {
    const int lane = threadIdx.x & 63;
    const int m = lane & 15, quad = lane >> 4;
    const int nTiles = (N + 15) >> 4;

    f16x8 w1f[2][4], w2f[2][4];
#pragma unroll
    for (int kh = 0; kh < 2; ++kh)
#pragma unroll
        for (int nt = 0; nt < 4; ++nt) {
            f16x8 a, b;
#pragma unroll
            for (int j = 0; j < 8; ++j) {
                int k = kh * 32 + quad * 8 + j;
                a[j] = (_Float16)W1[k * 64 + nt * 16 + m];
                b[j] = (_Float16)W2[k * 64 + nt * 16 + m];
            }
            w1f[kh][nt] = a;
            w2f[kh][nt] = b;
        }
    float bv[4];
#pragma unroll
    for (int nt = 0; nt < 4; ++nt) bv[nt] = b2[nt * 16 + m];

    for (int t = wid; t < nTiles; t += nwaves) {
        int row = t * 16 + m;
        f16x8 alo = {}, ahi = {};
        if (row < N) {
            if (HALF_IN) {
                const f16x8* A8 = (const f16x8*)Av;
                alo = __builtin_nontemporal_load(A8 + (size_t)row * 8 + quad);
                ahi = __builtin_nontemporal_load(A8 + (size_t)row * 8 + 4 + quad);
            } else {
                const f32x4* p = (const f32x4*)((const float*)Av + (size_t)row * 64);
                f32x4 x0 = __builtin_nontemporal_load(p + quad * 2);
                f32x4 x1 = __builtin_nontemporal_load(p + quad * 2 + 1);
                f32x4 x2 = __builtin_nontemporal_load(p + 8 + quad * 2);
                f32x4 x3 = __builtin_nontemporal_load(p + 8 + quad * 2 + 1);
                alo[0] = (_Float16)x0[0]; alo[1] = (_Float16)x0[1];
                alo[2] = (_Float16)x0[2]; alo[3] = (_Float16)x0[3];
                alo[4] = (_Float16)x1[0]; alo[5] = (_Float16)x1[1];
                alo[6] = (_Float16)x1[2]; alo[7] = (_Float16)x1[3];
                ahi[0] = (_Float16)x2[0]; ahi[1] = (_Float16)x2[1];
                ahi[2] = (_Float16)x2[2]; ahi[3] = (_Float16)x2[3];
                ahi[4] = (_Float16)x3[0]; ahi[5] = (_Float16)x3[1];
                ahi[6] = (_Float16)x3[2]; ahi[7] = (_Float16)x3[3];
            }
        }
#pragma unroll
        for (int nt = 0; nt < 4; ++nt) {
            f32x4 a1 = {0.f, 0.f, 0.f, 0.f}, a2 = {0.f, 0.f, 0.f, 0.f};
            a1 = MFMA16(alo, w1f[0][nt], a1);
            a1 = MFMA16(ahi, w1f[1][nt], a1);
            a2 = MFMA16(alo, w2f[0][nt], a2);
            a2 = MFMA16(ahi, w2f[1][nt], a2);
#pragma unroll
            for (int r = 0; r < 4; ++r) {
                int orow = t * 16 + quad * 4 + r;
                if (orow < N) {
                    C1[(size_t)orow * 64 + nt * 16 + m] = (_Float16)a1[r];
                    C2[(size_t)orow * 64 + nt * 16 + m] = (_Float16)(a2[r] + bv[nt]);
                }
            }
        }
    }
}

// ---- MFMA xt device body: C = A(f32)@W + bias + addend(f32), f16 out ----
__device__ __forceinline__ void mfma_xt_dev(const float* __restrict__ A,
                                            const float* __restrict__ W,
                                            const float* __restrict__ bias,
                                            const float* __restrict__ addend,
                                            _Float16* __restrict__ C,
                                            int N, int wid, int nwaves) {
    const int lane = threadIdx.x & 63;
    const int m = lane & 15, quad = lane >> 4;
    const int nTiles = (N + 15) >> 4;

    f16x8 wf[2][4];
#pragma unroll
    for (int kh = 0; kh < 2; ++kh)
#pragma unroll
        for (int nt = 0; nt < 4; ++nt) {
            f16x8 a;
#pragma unroll
            for (int j = 0; j < 8; ++j) {
                int k = kh * 32 + quad * 8 + j;
                a[j] = (_Float16)W[k * 64 + nt * 16 + m];
            }
            wf[kh][nt] = a;
        }
    float bv[4];
#pragma unroll
    for (int nt = 0; nt < 4; ++nt) bv[nt] = bias[nt * 16 + m];

    for (int t = wid; t < nTiles; t += nwaves) {
        int row = t * 16 + m;
        f16x8 alo = {}, ahi = {};
        if (row < N) {
            const f32x4* p = (const f32x4*)(A + (size_t)row * 64);
            f32x4 x0 = __builtin_nontemporal_load(p + quad * 2);
            f32x4 x1 = __builtin_nontemporal_load(p + quad * 2 + 1);
            f32x4 x2 = __builtin_nontemporal_load(p + 8 + quad * 2);
            f32x4 x3 = __builtin_nontemporal_load(p + 8 + quad * 2 + 1);
            alo[0] = (_Float16)x0[0]; alo[1] = (_Float16)x0[1];
            alo[2] = (_Float16)x0[2]; alo[3] = (_Float16)x0[3];
            alo[4] = (_Float16)x1[0]; alo[5] = (_Float16)x1[1];
            alo[6] = (_Float16)x1[2]; alo[7] = (_Float16)x1[3];
            ahi[0] = (_Float16)x2[0]; ahi[1] = (_Float16)x2[1];
            ahi[2] = (_Float16)x2[2]; ahi[3] = (_Float16)x2[3];
            ahi[4] = (_Float16)x3[0]; ahi[5] = (_Float16)x3[1];
            ahi[6] = (_Float16)x3[2]; ahi[7] = (_Float16)x3[3];
        }
#pragma unroll
        for (int nt = 0; nt < 4; ++nt) {
            f32x4 a1 = {0.f, 0.f, 0.f, 0.f};
            a1 = MFMA16(alo, wf[0][nt], a1);
            a1 = MFMA16(ahi, wf[1][nt], a1);
#pragma unroll
            for (int r = 0; r < 4; ++r) {
                int orow = t * 16 + quad * 4 + r;
                if (orow < N) {
                    float ad = __builtin_nontemporal_load(
                        &addend[(size_t)orow * 64 + nt * 16 + m]);
                    C[(size_t)orow * 64 + nt * 16 + m] = (_Float16)(a1[r] + bv[nt] + ad);
                }
            }
        }
    }
}

// in-place inclusive scan over sc[0..511] (counts pre-loaded), 256 threads
__device__ __forceinline__ void block_scan512(int* sc, int tid) {
    for (int off = 1; off < 512; off <<= 1) {
        int i0 = tid, i1 = tid + 256;
        int v0 = (i0 >= off) ? sc[i0 - off] : 0;
        int v1 = (i1 >= off) ? sc[i1 - off] : 0;
        __syncthreads();
        sc[i0] += v0;
        sc[i1] += v1;
        __syncthreads();
    }
}

// ---- K_A: fused [bin (LDS sort-then-stream) | xt GEMM] -----------------
__global__ void __launch_bounds__(256) k_bin_xt(
    const int* __restrict__ src, const int* __restrict__ dst,
    int* __restrict__ curT, int* __restrict__ curP,
    unsigned* __restrict__ binT, unsigned* __restrict__ binP,
    int BT, int BP, int E, int nbBin,
    const float* __restrict__ A, const float* __restrict__ W,
    const float* __restrict__ bias, const float* __restrict__ addend,
    _Float16* __restrict__ C, int NT_, int xtBlocks) {
    __shared__ int cT[BMAX], cP[BMAX], oT[BMAX], oP[BMAX], cur[BMAX];
    __shared__ int sc[512];
    __shared__ unsigned stage[EPB];
    int tid = threadIdx.x;
    if ((int)blockIdx.x >= nbBin) {
        int xb = blockIdx.x - nbBin;
        mfma_xt_dev(A, W, bias, addend, C, NT_, xb * 4 + (tid >> 6), xtBlocks * 4);
        return;
    }
    const int wave = tid >> 6, lane = tid & 63;
    for (int i = tid; i < BMAX; i += 256) { cT[i] = 0; cP[i] = 0; }
    __syncthreads();
    int e0 = blockIdx.x * EPB;
    int ls[EPB / 256], ld[EPB / 256];
#pragma unroll
    for (int k = 0; k < EPB / 256; ++k) {
        int i = e0 + k * 256 + tid;
        if (i < E) {
            ls[k] = __builtin_nontemporal_load(&src[i]);
            ld[k] = __builtin_nontemporal_load(&dst[i]);
            atomicAdd(&cT[ld[k] >> 8], 1);
            atomicAdd(&cP[ls[k] >> 9], 1);
        }
    }
    __syncthreads();
    // grab global chunks
    for (int b = tid; b < BT; b += 256) { int c = cT[b]; oT[b] = c ? atomicAdd(&curT[b], c) : 0; }
    for (int b = tid; b < BP; b += 256) { int c = cP[b]; oP[b] = c ? atomicAdd(&curP[b], c) : 0; }
    // ---- T side: scan, scatter to LDS, stream out ----
    sc[tid]       = (tid < BT) ? cT[tid] : 0;
    sc[tid + 256] = (tid + 256 < BT) ? cT[tid + 256] : 0;
    __syncthreads();
    block_scan512(sc, tid);
    for (int b = tid; b < BT; b += 256) cur[b] = sc[b] - cT[b];
    __syncthreads();
#pragma unroll
    for (int k = 0; k < EPB / 256; ++k) {
        int i = e0 + k * 256 + tid;
        if (i < E) {
            int bt = ld[k] >> 8;
            int pos = atomicAdd(&cur[bt], 1);
            stage[pos] = ((unsigned)(ld[k] & 255) << LSHT) | (unsigned)ls[k];
        }
    }
    __syncthreads();
    for (int b = wave; b < BT; b += 4) {
        int cnt = cT[b], so = sc[b] - cnt, go = oT[b];
        for (int i = lane; i < cnt; i += 64) {
            int pos = go + i;
            if (pos < CAPB) binT[(size_t)b * CAPB + pos] = stage[so + i];
        }
    }
    __syncthreads();
    // ---- P side ----
    sc[tid]       = (tid < BP) ? cP[tid] : 0;
    sc[tid + 256] = (tid + 256 < BP) ? cP[tid + 256] : 0;
    __syncthreads();
    block_scan512(sc, tid);
    for (int b = tid; b < BP; b += 256) cur[b] = sc[b] - cP[b];
    __syncthreads();
#pragma unroll
    for (int k = 0; k < EPB / 256; ++k) {
        int i = e0 + k * 256 + tid;
        if (i < E) {
            int bp = ls[k] >> 9;
            int pos = atomicAdd(&cur[bp], 1);
            stage[pos] = ((unsigned)(ls[k] & 511) << LSHP) | (unsigned)ld[k];
        }
    }
    __syncthreads();
    for (int b = wave; b < BP; b += 4) {
        int cnt = cP[b], so = sc[b] - cnt, go = oP[b];
        for (int i = lane; i < cnt; i += 64) {
            int pos = go + i;
            if (pos < CAPB) binP[(size_t)b * CAPB + pos] = stage[so + i];
        }
    }
}

// ---- CSR per-bucket device body: scatter into LDS, stream out int4 -----
__device__ __forceinline__ void csr_dev(const unsigned* __restrict__ binned,
                                        const int* __restrict__ cur,
                                        int* __restrict__ start_g, int* __restrict__ cnt_g,
                                        int* __restrict__ adj,
                                        int S, int lshift, int N, int b,
                                        int* lcnt, int* lscan, int* lcur, int* adj_lds) {
    int tid = threadIdx.x;
    int base = b * CAPB;
    int n = cur[b]; if (n > CAPB) n = CAPB;
    int rowlo = b * S;
    unsigned nbmask = (1u << lshift) - 1u;

    for (int i = tid; i < S; i += 256) lcnt[i] = 0;
    __syncthreads();
    for (int i = tid; i < n; i += 256)
        atomicAdd(&lcnt[binned[base + i] >> lshift], 1);
    __syncthreads();
    for (int i = tid; i < S; i += 256) lscan[i] = lcnt[i];
    __syncthreads();
    for (int off = 1; off < S; off <<= 1) {
        int i0 = tid, i1 = tid + 256;
        int v0 = (i0 >= off) ? lscan[i0 - off] : 0;
        int v1 = (S > 256 && i1 >= off) ? lscan[i1 - off] : 0;
        __syncthreads();
        if (i0 < S) lscan[i0] += v0;
        if (S > 256 && i1 < S) lscan[i1] += v1;
        __syncthreads();
    }
    for (int r = tid; r < S; r += 256) {
        int ex = lscan[r] - lcnt[r];
        lcur[r] = ex;
        int row = rowlo + r;
        if (row < N) {
            start_g[row] = base + ex;
            cnt_g[row]   = lcnt[r];
        }
    }
    __syncthreads();
    for (int i = tid; i < n; i += 256) {
        unsigned e = binned[base + i];
        int r = e >> lshift;
        int pos = atomicAdd(&lcur[r], 1);
        adj_lds[pos] = (int)(e & nbmask);
    }
    __syncthreads();
    int n4 = n & ~3;
    for (int i = tid * 4; i < n4; i += 1024)
        *(int4*)&adj[base + i] = *(const int4*)&adj_lds[i];
    for (int i = n4 + tid; i < n; i += 256)
        adj[base + i] = adj_lds[i];
}

// ---- K_B: fused [csr-t | csr-p | layer-1 MFMA pair] --------------------
__global__ void __launch_bounds__(256) k_csr_mfma1(
    const unsigned* __restrict__ binT, const unsigned* __restrict__ binP,
    const int* __restrict__ curT, const int* __restrict__ curP,
    int* __restrict__ start_t, int* __restrict__ cnt_t, int* __restrict__ adj_t,
    int* __restrict__ start_p, int* __restrict__ cnt_p, int* __restrict__ adj_p,
    int BT, int BP, int NT_, int NP_,
    const _Float16* __restrict__ XTh, const float* __restrict__ Wt1, const float* __restrict__ Wt2,
    const float* __restrict__ bt2, _Float16* __restrict__ Aht, _Float16* __restrict__ Bth,
    const float* __restrict__ pemb, const float* __restrict__ Wp1, const float* __restrict__ Wp2,
    const float* __restrict__ bp2, _Float16* __restrict__ Ahp, _Float16* __restrict__ Bph,
    int tB, int pB) {
    __shared__ int lcnt[512], lscan[512], lcur[512];
    __shared__ int adj_lds[CAPB];
    int bi = blockIdx.x;
    if (bi < BT) {
        csr_dev(binT, curT, start_t, cnt_t, adj_t, ST, LSHT, NT_, bi, lcnt, lscan, lcur, adj_lds);
    } else if (bi < BT + BP) {
        csr_dev(binP, curP, start_p, cnt_p, adj_p, SP, LSHP, NP_, bi - BT, lcnt, lscan, lcur, adj_lds);
    } else if (bi < BT + BP + tB) {
        int wb = bi - BT - BP;
        mfma_dual_dev<1>(XTh, Wt1, Wt2, bt2, Aht, Bth, NT_, wb * 4 + (threadIdx.x >> 6), tB * 4);
    } else {
        int wb = bi - BT - BP - tB;
        mfma_dual_dev<0>(pemb, Wp1, Wp2, bp2, Ahp, Bph, NP_, wb * 4 + (threadIdx.x >> 6), pB * 4);
    }
}

// ---- weight staging: pre-swizzled per-lane MFMA B-fragments into LDS ----
// layout: frag[(tbl*8 + kh*4 + nt)*64 + lane] = 8 f16 (fragment for that lane)
__device__ __forceinline__ void stage_w_lds(half8v* ldsW,
                                            const float* __restrict__ W1,
                                            const float* __restrict__ W2, int tid) {
    for (int f = tid; f < 1024; f += 256) {
        int lane = f & 63, nt = (f >> 6) & 3, kh = (f >> 8) & 1, tbl = f >> 9;
        int m = lane & 15, quad = lane >> 4;
        const float* W = tbl ? W2 : W1;
        half8v frag;
#pragma unroll
        for (int j = 0; j < 8; ++j) {
            int k = kh * 32 + quad * 8 + j;
            frag[j] = (_Float16)W[k * 64 + nt * 16 + m];
        }
        ldsW[f] = frag;
    }
}

// ---- fused gather-mean + relu + dual GEMM (one 16-row tile per wave) ----
// Gather in MFMA A-fragment layout: lane (m,quad) owns row tile*16+m,
// feature chunks [quad*8..+7] (lo) and [32+quad*8..+7] (hi).
// Then C1 = relu(mean+B) @ W1, C2 = relu(mean+B) @ W2 + b2, f16 out.
__device__ __forceinline__ void gather_gemm_dev(
    const int* __restrict__ adj, const int* __restrict__ start, const int* __restrict__ cnt,
    const _Float16* __restrict__ A, const _Float16* __restrict__ B,
    const half8v* __restrict__ ldsW, const float* __restrict__ b2,
    _Float16* __restrict__ C1, _Float16* __restrict__ C2,
    int N, int tile) {
    const int lane = threadIdx.x & 63;
    const int m = lane & 15, quad = lane >> 4;
    const int row = tile * 16 + m;

    half8v accl = {}, acch = {};
    int dg = 0;
    if (row < N) {
        int st = __builtin_nontemporal_load(&start[row]);
        dg     = __builtin_nontemporal_load(&cnt[row]);
        const half8v* A8 = (const half8v*)A;
        int j = 0;
        for (; j + 3 < dg; j += 4) {  // 4 neighbors x 2 chunks = 8 loads in flight
            int n0 = __builtin_nontemporal_load(&adj[st + j]);
            int n1 = __builtin_nontemporal_load(&adj[st + j + 1]);
            int n2 = __builtin_nontemporal_load(&adj[st + j + 2]);
            int n3 = __builtin_nontemporal_load(&adj[st + j + 3]);
            half8v l0 = A8[(size_t)n0 * 8 + quad];
            half8v h0 = A8[(size_t)n0 * 8 + 4 + quad];
            half8v l1 = A8[(size_t)n1 * 8 + quad];
            half8v h1 = A8[(size_t)n1 * 8 + 4 + quad];
            half8v l2 = A8[(size_t)n2 * 8 + quad];
            half8v h2 = A8[(size_t)n2 * 8 + 4 + quad];
            half8v l3 = A8[(size_t)n3 * 8 + quad];
            half8v h3 = A8[(size_t)n3 * 8 + 4 + quad];
            accl += (l0 + l1) + (l2 + l3);
            acch += (h0 + h1) + (h2 + h3);
        }
        for (; j < dg; ++j) {
            int n = __builtin_nontemporal_load(&adj[st + j]);
            accl += A8[(size_t)n * 8 + quad];
            acch += A8[(size_t)n * 8 + 4 + quad];
        }
    }

    f16x8 alo = {}, ahi = {};
    if (row < N) {
        float inv = 1.0f / (float)(dg > 1 ? dg : 1);
        half8v bl = __builtin_nontemporal_load(&((const half8v*)B)[(size_t)row * 8 + quad]);
        half8v bh = __builtin_nontemporal_load(&((const half8v*)B)[(size_t)row * 8 + 4 + quad]);
#pragma unroll
        for (int k = 0; k < 8; ++k) {
            float vl = fmaxf((float)accl[k] * inv + (float)bl[k], 0.f);
            float vh = fmaxf((float)acch[k] * inv + (float)bh[k], 0.f);
            alo[k] = (_Float16)vl;
            ahi[k] = (_Float16)vh;
        }
    }

#pragma unroll
    for (int nt = 0; nt < 4; ++nt) {
        f16x8 w1l = (f16x8)ldsW[(0 * 8 + 0 * 4 + nt) * 64 + lane];
        f16x8 w1h = (f16x8)ldsW[(0 * 8 + 1 * 4 + nt) * 64 + lane];
        f16x8 w2l = (f16x8)ldsW[(1 * 8 + 0 * 4 + nt) * 64 + lane];
        f16x8 w2h = (f16x8)ldsW[(1 * 8 + 1 * 4 + nt) * 64 + lane];
        f32x4 a1 = {0.f, 0.f, 0.f, 0.f}, a2 = {0.f, 0.f, 0.f, 0.f};
        a1 = MFMA16(alo, w1l, a1);
        a1 = MFMA16(ahi, w1h, a1);
        a2 = MFMA16(alo, w2l, a2);
        a2 = MFMA16(ahi, w2h, a2);
        float bb = b2[nt * 16 + m];
#pragma unroll
        for (int r = 0; r < 4; ++r) {
            int orow = tile * 16 + quad * 4 + r;
            if (orow < N) {
                C1[(size_t)orow * 64 + nt * 16 + m] = (_Float16)a1[r];
                C2[(size_t)orow * 64 + nt * 16 + m] = (_Float16)(a2[r] + bb);
            }
        }
    }
}

// ---- K_CD: fused [layer-1 gather+relu+layer-2 dual GEMM], t | p --------
__global__ void __launch_bounds__(256) k_gather_gemm(
    const int* __restrict__ adjT, const int* __restrict__ startT, const int* __restrict__ cntT,
    const _Float16* __restrict__ At, const _Float16* __restrict__ Bt,
    const float* __restrict__ Wt1, const float* __restrict__ Wt2, const float* __restrict__ bt2,
    _Float16* __restrict__ C1t, _Float16* __restrict__ C2t, int NT_,
    const int* __restrict__ adjP, const int* __restrict__ startP, const int* __restrict__ cntP,
    const _Float16* __restrict__ Ap, const _Float16* __restrict__ Bp,
    const float* __restrict__ Wp1, const float* __restrict__ Wp2, const float* __restrict__ bp2,
    _Float16* __restrict__ C1p, _Float16* __restrict__ C2p, int NP_,
    int tTB) {
    __shared__ half8v ldsW[1024];  // 16 KiB: pre-swizzled weight fragments
    const int tid = threadIdx.x, wave = tid >> 6;
    if ((int)blockIdx.x < tTB) {
        stage_w_lds(ldsW, Wt1, Wt2, tid);
        __syncthreads();
        int tile = blockIdx.x * 4 + wave;
        if (tile < ((NT_ + 15) >> 4))
            gather_gemm_dev(adjT, startT, cntT, At, Bt, ldsW, bt2, C1t, C2t, NT_, tile);
    } else {
        stage_w_lds(ldsW, Wp1, Wp2, tid);
        __syncthreads();
        int tile = (blockIdx.x - tTB) * 4 + wave;
        if (tile < ((NP_ + 15) >> 4))
            gather_gemm_dev(adjP, startP, cntP, Ap, Bp, ldsW, bp2, C1p, C2p, NP_, tile);
    }
}

// ---- gather-mean device body: 8 lanes/row, 8 loads in flight -----------
// Output is consumed RANDOMLY by dot_h -> regular cached store (keep in L2/LLC).
__device__ __forceinline__ void gather_dev(
    const int* __restrict__ adj, const int* __restrict__ start, const int* __restrict__ cnt,
    const _Float16* __restrict__ A, const _Float16* __restrict__ B,
    _Float16* __restrict__ out, int do_relu, int N, int gidx) {
    int row = gidx >> 3;
    int c   = gidx & 7;
    if (row >= N) return;

    int st = __builtin_nontemporal_load(&start[row]);
    int dg = __builtin_nontemporal_load(&cnt[row]);
    const half8v* A8 = (const half8v*)A;
    half8v acc = {};
    int j = 0;
    for (; j + 7 < dg; j += 8) {  // 8 gathers in flight
        int n0 = __builtin_nontemporal_load(&adj[st + j]);
        int n1 = __builtin_nontemporal_load(&adj[st + j + 1]);
        int n2 = __builtin_nontemporal_load(&adj[st + j + 2]);
        int n3 = __builtin_nontemporal_load(&adj[st + j + 3]);
        int n4 = __builtin_nontemporal_load(&adj[st + j + 4]);
        int n5 = __builtin_nontemporal_load(&adj[st + j + 5]);
        int n6 = __builtin_nontemporal_load(&adj[st + j + 6]);
        int n7 = __builtin_nontemporal_load(&adj[st + j + 7]);
        half8v v0 = A8[(size_t)n0 * 8 + c];
        half8v v1 = A8[(size_t)n1 * 8 + c];
        half8v v2 = A8[(size_t)n2 * 8 + c];
        half8v v3 = A8[(size_t)n3 * 8 + c];
        half8v v4 = A8[(size_t)n4 * 8 + c];
        half8v v5 = A8[(size_t)n5 * 8 + c];
        half8v v6 = A8[(size_t)n6 * 8 + c];
        half8v v7 = A8[(size_t)n7 * 8 + c];
        acc += ((v0 + v1) + (v2 + v3)) + ((v4 + v5) + (v6 + v7));
    }
    if (j + 3 < dg) {
        int n0 = __builtin_nontemporal_load(&adj[st + j]);
        int n1 = __builtin_nontemporal_load(&adj[st + j + 1]);
        int n2 = __builtin_nontemporal_load(&adj[st + j + 2]);
        int n3 = __builtin_nontemporal_load(&adj[st + j + 3]);
        half8v v0 = A8[(size_t)n0 * 8 + c];
        half8v v1 = A8[(size_t)n1 * 8 + c];
        half8v v2 = A8[(size_t)n2 * 8 + c];
        half8v v3 = A8[(size_t)n3 * 8 + c];
        acc += (v0 + v1) + (v2 + v3);
        j += 4;
    }
    for (; j < dg; ++j)
        acc += A8[(size_t)__builtin_nontemporal_load(&adj[st + j]) * 8 + c];

    float inv = 1.0f / (float)(dg > 1 ? dg : 1);
    half8v b8 = __builtin_nontemporal_load(&((const half8v*)B)[(size_t)row * 8 + c]);
    half8v o;
#pragma unroll
    for (int k = 0; k < 8; ++k) {
        float v = (float)acc[k] * inv + (float)b8[k];
        if (do_relu) v = fmaxf(v, 0.f);
        o[k] = (_Float16)v;
    }
    ((half8v*)out)[(size_t)row * 8 + c] = o;
}

// ---- K_E: fused [gather-t | gather-p] ----------------------------------
__global__ void __launch_bounds__(256) k_gather2(
    const int* __restrict__ adjT, const int* __restrict__ startT, const int* __restrict__ cntT,
    const _Float16* __restrict__ At, const _Float16* __restrict__ Bt, _Float16* __restrict__ outT, int NT_,
    const int* __restrict__ adjP, const int* __restrict__ startP, const int* __restrict__ cntP,
    const _Float16* __restrict__ Ap, const _Float16* __restrict__ Bp, _Float16* __restrict__ outP, int NP_,
    int do_relu, int wTb) {
    if ((int)blockIdx.x < wTb)
        gather_dev(adjT, startT, cntT, At, Bt, outT, do_relu, NT_, blockIdx.x * 256 + threadIdx.x);
    else
        gather_dev(adjP, startP, cntP, Ap, Bp, outP, do_relu, NP_,
                   (blockIdx.x - wTb) * 256 + threadIdx.x);
}

// ---- classifier: 8 lanes/edge, v_dot2_f32_f16 --------------------------
__global__ void __launch_bounds__(256) dot_h(const _Float16* __restrict__ p2,
                                             const _Float16* __restrict__ t2,
                                             const int* __restrict__ els,
                                             const int* __restrict__ eld,
                                             float* __restrict__ out, int EL) {
    int tid = blockIdx.x * 256 + threadIdx.x;
    int i = tid >> 3, c = tid & 7;
    if (i < EL) {
        int s = __builtin_nontemporal_load(&els[i]);
        int d = __builtin_nontemporal_load(&eld[i]);
        half8v a = ((const half8v*)p2)[(size_t)s * 8 + c];
        half8v b = ((const half8v*)t2)[(size_t)d * 8 + c];
        float v = 0.f;
#ifdef HAS_FDOT2
        const half2v* ap = (const half2v*)&a;
        const half2v* bp = (const half2v*)&b;
#pragma unroll
        for (int k = 0; k < 4; ++k) v = __builtin_amdgcn_fdot2(ap[k], bp[k], v, false);
#else
#pragma unroll
        for (int k = 0; k < 8; ++k) v += (float)a[k] * (float)b[k];
#endif
        v += __shfl_xor(v, 1, 64);
        v += __shfl_xor(v, 2, 64);
        v += __shfl_xor(v, 4, 64);
        if (c == 0) __builtin_nontemporal_store(v, &out[i]);
    }
}

extern "C" void kernel_launch(void* const* d_in, const int* in_sizes, int n_in,
                              void* d_out, int out_size, void* d_ws, size_t ws_size,
                              hipStream_t stream) {
    const float* x_taxon  = (const float*)d_in[0];
    const float* tlw      = (const float*)d_in[1];
    const float* tlb      = (const float*)d_in[2];
    const float* pemb     = (const float*)d_in[3];
    const float* temb     = (const float*)d_in[4];
    const int*   edge_src = (const int*)d_in[7];
    const int*   edge_dst = (const int*)d_in[8];
    const int*   el_src   = (const int*)d_in[9];
    const int*   el_dst   = (const int*)d_in[10];
    const float* c1pt_wl  = (const float*)d_in[11];
    const float* c1pt_wr  = (const float*)d_in[12];
    const float* c1tp_wl  = (const float*)d_in[13];
    const float* c1tp_wr  = (const float*)d_in[14];
    const float* c2pt_wl  = (const float*)d_in[15];
    const float* c2pt_wr  = (const float*)d_in[16];
    const float* c2tp_wl  = (const float*)d_in[17];
    const float* c2tp_wr  = (const float*)d_in[18];
    const float* c1pt_bl  = (const float*)d_in[19];
    const float* c1tp_bl  = (const float*)d_in[20];
    const float* c2pt_bl  = (const float*)d_in[21];
    const float* c2tp_bl  = (const float*)d_in[22];

    const int NP_ = in_sizes[5];
    const int NT_ = in_sizes[6];
    const int E_  = in_sizes[7];
    const int EL_ = in_sizes[9];
    const int BT  = (NT_ + ST - 1) / ST;   // 391
    const int BP  = (NP_ + SP - 1) / SP;   // 391

    // workspace (same 4*NT + 4*NP f16-row footprint as before):
    //   XTh  [NT]: K_A out, K_B in; then Aht2 alias (K_CD out, K_E in)
    //   Aht1 [NT]: K_B out, K_CD p-gather table; then T2h alias (K_E out)
    //   Bth1 [NT]: K_B out, K_CD t-addend
    //   Bth2 [NT]: K_CD out, K_E t-addend
    //   Ahp1 [NP]: K_B out, K_CD t-gather table; then P2h alias (K_E out)
    //   Bph1 [NP]: K_B out, K_CD p-addend
    //   Ahp2 [NP]: K_CD out, K_E t-gather table
    //   Bph2 [NP]: K_CD out, K_E p-addend
    _Float16* hb   = (_Float16*)d_ws;
    _Float16* XTh  = hb;
    _Float16* Aht1 = XTh + (size_t)NT_ * H;
    _Float16* Bth1 = Aht1 + (size_t)NT_ * H;
    _Float16* Bth2 = Bth1 + (size_t)NT_ * H;
    _Float16* Ahp1 = Bth2 + (size_t)NT_ * H;
    _Float16* Bph1 = Ahp1 + (size_t)NP_ * H;
    _Float16* Ahp2 = Bph1 + (size_t)NP_ * H;
    _Float16* Bph2 = Ahp2 + (size_t)NP_ * H;
    _Float16* Aht2 = XTh;    // alias: XTh dead after K_B
    _Float16* T2h  = Aht1;   // alias: Aht1 dead after K_CD
    _Float16* P2h  = Ahp1;   // alias: Ahp1 dead after K_CD

    unsigned* binT    = (unsigned*)(Bph2 + (size_t)NP_ * H);  // BT*CAPB
    unsigned* binP    = binT + (size_t)BT * CAPB;             // BP*CAPB
    int*      adj_t   = (int*)(binP + (size_t)BP * CAPB);     // BT*CAPB
    int*      adj_p   = adj_t + (size_t)BT * CAPB;            // BP*CAPB
    int* start_t = adj_p + (size_t)BP * CAPB;  // NT
    int* start_p = start_t + NT_;              // NP
    int* cnt_t   = start_p + NP_;              // NT
    int* cnt_p   = cnt_t + NT_;                // NP
    int* curT    = cnt_p + NP_;                // BMAX
    int* curP    = curT + BMAX;                // BMAX

    (void)hipMemsetAsync(curT, 0, 2 * BMAX * sizeof(int), stream);

    const int nbBin = (E_ + EPB - 1) / EPB;              // 489
    const int XTB   = 512;                               // xt GEMM blocks
    const int wT = (NT_ * 8 + 255) / 256, wP = (NP_ * 8 + 255) / 256;
    const int tB = 256, pB = 512;                        // MFMA pair split (tiles 1:2)

    // K_A: bin (blocks 0..nbBin, dispatched first => owns the CUs early) + xt GEMM
    k_bin_xt<<<nbBin + XTB, 256, 0, stream>>>(
        edge_src, edge_dst, curT, curP, binT, binP, BT, BP, E_, nbBin,
        x_taxon, tlw, tlb, temb, XTh, NT_, XTB);

    // K_B: csr-t + csr-p + layer-1 MFMA pair
    //   Aht1 = XT@c1tp_wl, Bth1 = XT@c1pt_wr + c1pt_bl
    //   Ahp1 = pemb@c1pt_wl, Bph1 = pemb@c1tp_wr + c1tp_bl
    k_csr_mfma1<<<BT + BP + tB + pB, 256, 0, stream>>>(
        binT, binP, curT, curP,
        start_t, cnt_t, adj_t, start_p, cnt_p, adj_p, BT, BP, NT_, NP_,
        XTh, c1tp_wl, c1pt_wr, c1pt_bl, Aht1, Bth1,
        pemb, c1pt_wl, c1tp_wr, c1tp_bl, Ahp1, Bph1, tB, pB);

    // K_CD: fused layer-1 gather (+relu) + layer-2 dual GEMM
    //   t: t1 = relu(mean(Ahp1)+Bth1); Aht2 = t1@c2tp_wl; Bth2 = t1@c2pt_wr + c2pt_bl
    //   p: p1 = relu(mean(Aht1)+Bph1); Ahp2 = p1@c2pt_wl; Bph2 = p1@c2tp_wr + c2tp_bl
    const int tTB = (((NT_ + 15) >> 4) + 3) >> 2;
    const int pTB = (((NP_ + 15) >> 4) + 3) >> 2;
    k_gather_gemm<<<tTB + pTB, 256, 0, stream>>>(
        adj_t, start_t, cnt_t, Ahp1, Bth1, c2tp_wl, c2pt_wr, c2pt_bl, Aht2, Bth2, NT_,
        adj_p, start_p, cnt_p, Aht1, Bph1, c2pt_wl, c2tp_wr, c2tp_bl, Ahp2, Bph2, NP_,
        tTB);

    // K_E: layer-2 gathers (no relu)
    //   t2 = mean(Ahp2)+Bth2 -> T2h ; p2 = mean(Aht2)+Bph2 -> P2h
    k_gather2<<<wT + wP, 256, 0, stream>>>(
        adj_t, start_t, cnt_t, Ahp2, Bth2, T2h, NT_,
        adj_p, start_p, cnt_p, Aht2, Bph2, P2h, NP_, 0, wT);

    // classifier
    dot_h<<<(EL_ * 8 + 255) / 256, 256, 0, stream>>>(P2h, T2h, el_src, el_dst,
                                                     (float*)d_out, EL_);
}

// Round 6
// 476.744 us; speedup vs baseline: 1.0588x; 1.0588x over previous
//
#include <hip/hip_runtime.h>

#define H 64
#define EPB 4096        // edges per bin block (489 blocks)
#define BMAX 400        // >= bucket count (391)
#define ST 256          // taxon rows per bucket
#define SP 512          // palmprint rows per bucket
#define LSHT 18         // t-entry: (dst&255)<<18 | src
#define LSHP 17         // p-entry: (src&511)<<17 | dst
#define CAPB 5632       // bucket capacity (mean 5120 + 7 sigma); %4==0

typedef _Float16 half2v __attribute__((ext_vector_type(2)));
typedef _Float16 half8v __attribute__((ext_vector_type(8)));
typedef _Float16 f16x8  __attribute__((ext_vector_type(8)));
typedef float    f32x4  __attribute__((ext_vector_type(4)));
typedef int      i32x4  __attribute__((ext_vector_type(4)));

#if defined(__has_builtin)
#if __has_builtin(__builtin_amdgcn_fdot2)
#define HAS_FDOT2 1
#endif
#endif

#define MFMA16(a, b, c) __builtin_amdgcn_mfma_f32_16x16x32_f16(a, b, c, 0, 0, 0)

// ---- MFMA dual GEMM device body: C1 = A@W1, C2 = A@W2 + b2 (f16 out) ----
template <int HALF_IN>
__device__ __forceinline__ void mfma_dual_dev(const void* __restrict__ Av,
                                              const float* __restrict__ W1,
                                              const float* __restrict__ W2,
                                              const float* __restrict__ b2,
                                              _Float16* __restrict__ C1,
                                              _Float16* __restrict__ C2,
                                              int N, int wid, int nwaves) {
    const int lane = threadIdx.x & 63;
    const int m = lane & 15, quad = lane >> 4;
    const int nTiles = (N + 15) >> 4;

    f16x8 w1f[2][4], w2f[2][4];
#pragma unroll
    for (int kh = 0; kh < 2; ++kh)
#pragma unroll
        for (int nt = 0; nt < 4; ++nt) {
            f16x8 a, b;
#pragma unroll
            for (int j = 0; j < 8; ++j) {
                int k = kh * 32 + quad * 8 + j;
                a[j] = (_Float16)W1[k * 64 + nt * 16 + m];
                b[j] = (_Float16)W2[k * 64 + nt * 16 + m];
            }
            w1f[kh][nt] = a;
            w2f[kh][nt] = b;
        }
    float bv[4];
#pragma unroll
    for (int nt = 0; nt < 4; ++nt) bv[nt] = b2[nt * 16 + m];

    for (int t = wid; t < nTiles; t += nwaves) {
        int row = t * 16 + m;
        f16x8 alo = {}, ahi = {};
        if (row < N) {
            if (HALF_IN) {
                const f16x8* A8 = (const f16x8*)Av;
                alo = __builtin_nontemporal_load(A8 + (size_t)row * 8 + quad);
                ahi = __builtin_nontemporal_load(A8 + (size_t)row * 8 + 4 + quad);
            } else {
                const f32x4* p = (const f32x4*)((const float*)Av + (size_t)row * 64);
                f32x4 x0 = __builtin_nontemporal_load(p + quad * 2);
                f32x4 x1 = __builtin_nontemporal_load(p + quad * 2 + 1);
                f32x4 x2 = __builtin_nontemporal_load(p + 8 + quad * 2);
                f32x4 x3 = __builtin_nontemporal_load(p + 8 + quad * 2 + 1);
                alo[0] = (_Float16)x0[0]; alo[1] = (_Float16)x0[1];
                alo[2] = (_Float16)x0[2]; alo[3] = (_Float16)x0[3];
                alo[4] = (_Float16)x1[0]; alo[5] = (_Float16)x1[1];
                alo[6] = (_Float16)x1[2]; alo[7] = (_Float16)x1[3];
                ahi[0] = (_Float16)x2[0]; ahi[1] = (_Float16)x2[1];
                ahi[2] = (_Float16)x2[2]; ahi[3] = (_Float16)x2[3];
                ahi[4] = (_Float16)x3[0]; ahi[5] = (_Float16)x3[1];
                ahi[6] = (_Float16)x3[2]; ahi[7] = (_Float16)x3[3];
            }
        }
#pragma unroll
        for (int nt = 0; nt < 4; ++nt) {
            f32x4 a1 = {0.f, 0.f, 0.f, 0.f}, a2 = {0.f, 0.f, 0.f, 0.f};
            a1 = MFMA16(alo, w1f[0][nt], a1);
            a1 = MFMA16(ahi, w1f[1][nt], a1);
            a2 = MFMA16(alo, w2f[0][nt], a2);
            a2 = MFMA16(ahi, w2f[1][nt], a2);
#pragma unroll
            for (int r = 0; r < 4; ++r) {
                int orow = t * 16 + quad * 4 + r;
                if (orow < N) {
                    C1[(size_t)orow * 64 + nt * 16 + m] = (_Float16)a1[r];
                    C2[(size_t)orow * 64 + nt * 16 + m] = (_Float16)(a2[r] + bv[nt]);
                }
            }
        }
    }
}

// ---- MFMA xt device body: C = A(f32)@W + bias + addend(f32), f16 out ----
__device__ __forceinline__ void mfma_xt_dev(const float* __restrict__ A,
                                            const float* __restrict__ W,
                                            const float* __restrict__ bias,
                                            const float* __restrict__ addend,
                                            _Float16* __restrict__ C,
                                            int N, int wid, int nwaves) {
    const int lane = threadIdx.x & 63;
    const int m = lane & 15, quad = lane >> 4;
    const int nTiles = (N + 15) >> 4;

    f16x8 wf[2][4];
#pragma unroll
    for (int kh = 0; kh < 2; ++kh)
#pragma unroll
        for (int nt = 0; nt < 4; ++nt) {
            f16x8 a;
#pragma unroll
            for (int j = 0; j < 8; ++j) {
                int k = kh * 32 + quad * 8 + j;
                a[j] = (_Float16)W[k * 64 + nt * 16 + m];
            }
            wf[kh][nt] = a;
        }
    float bv[4];
#pragma unroll
    for (int nt = 0; nt < 4; ++nt) bv[nt] = bias[nt * 16 + m];

    for (int t = wid; t < nTiles; t += nwaves) {
        int row = t * 16 + m;
        f16x8 alo = {}, ahi = {};
        if (row < N) {
            const f32x4* p = (const f32x4*)(A + (size_t)row * 64);
            f32x4 x0 = __builtin_nontemporal_load(p + quad * 2);
            f32x4 x1 = __builtin_nontemporal_load(p + quad * 2 + 1);
            f32x4 x2 = __builtin_nontemporal_load(p + 8 + quad * 2);
            f32x4 x3 = __builtin_nontemporal_load(p + 8 + quad * 2 + 1);
            alo[0] = (_Float16)x0[0]; alo[1] = (_Float16)x0[1];
            alo[2] = (_Float16)x0[2]; alo[3] = (_Float16)x0[3];
            alo[4] = (_Float16)x1[0]; alo[5] = (_Float16)x1[1];
            alo[6] = (_Float16)x1[2]; alo[7] = (_Float16)x1[3];
            ahi[0] = (_Float16)x2[0]; ahi[1] = (_Float16)x2[1];
            ahi[2] = (_Float16)x2[2]; ahi[3] = (_Float16)x2[3];
            ahi[4] = (_Float16)x3[0]; ahi[5] = (_Float16)x3[1];
            ahi[6] = (_Float16)x3[2]; ahi[7] = (_Float16)x3[3];
        }
#pragma unroll
        for (int nt = 0; nt < 4; ++nt) {
            f32x4 a1 = {0.f, 0.f, 0.f, 0.f};
            a1 = MFMA16(alo, wf[0][nt], a1);
            a1 = MFMA16(ahi, wf[1][nt], a1);
#pragma unroll
            for (int r = 0; r < 4; ++r) {
                int orow = t * 16 + quad * 4 + r;
                if (orow < N) {
                    float ad = __builtin_nontemporal_load(
                        &addend[(size_t)orow * 64 + nt * 16 + m]);
                    C[(size_t)orow * 64 + nt * 16 + m] = (_Float16)(a1[r] + bv[nt] + ad);
                }
            }
        }
    }
}

// in-place inclusive scan over sc[0..511] (counts pre-loaded), 256 threads
__device__ __forceinline__ void block_scan512(int* sc, int tid) {
    for (int off = 1; off < 512; off <<= 1) {
        int i0 = tid, i1 = tid + 256;
        int v0 = (i0 >= off) ? sc[i0 - off] : 0;
        int v1 = (i1 >= off) ? sc[i1 - off] : 0;
        __syncthreads();
        sc[i0] += v0;
        sc[i1] += v1;
        __syncthreads();
    }
}

// ---- K_A: fused [bin (LDS sort-then-stream) | xt GEMM] -----------------
__global__ void __launch_bounds__(256) k_bin_xt(
    const int* __restrict__ src, const int* __restrict__ dst,
    int* __restrict__ curT, int* __restrict__ curP,
    unsigned* __restrict__ binT, unsigned* __restrict__ binP,
    int BT, int BP, int E, int nbBin,
    const float* __restrict__ A, const float* __restrict__ W,
    const float* __restrict__ bias, const float* __restrict__ addend,
    _Float16* __restrict__ C, int NT_, int xtBlocks) {
    __shared__ int cT[BMAX], cP[BMAX], oT[BMAX], oP[BMAX], cur[BMAX];
    __shared__ int sc[512];
    __shared__ unsigned stage[EPB];
    int tid = threadIdx.x;
    if ((int)blockIdx.x >= nbBin) {
        int xb = blockIdx.x - nbBin;
        mfma_xt_dev(A, W, bias, addend, C, NT_, xb * 4 + (tid >> 6), xtBlocks * 4);
        return;
    }
    const int wave = tid >> 6, lane = tid & 63;
    for (int i = tid; i < BMAX; i += 256) { cT[i] = 0; cP[i] = 0; }
    __syncthreads();
    int e0 = blockIdx.x * EPB;
    int ls[EPB / 256], ld[EPB / 256];
#pragma unroll
    for (int k = 0; k < EPB / 256; ++k) {
        int i = e0 + k * 256 + tid;
        if (i < E) {
            ls[k] = __builtin_nontemporal_load(&src[i]);
            ld[k] = __builtin_nontemporal_load(&dst[i]);
            atomicAdd(&cT[ld[k] >> 8], 1);
            atomicAdd(&cP[ls[k] >> 9], 1);
        }
    }
    __syncthreads();
    // grab global chunks
    for (int b = tid; b < BT; b += 256) { int c = cT[b]; oT[b] = c ? atomicAdd(&curT[b], c) : 0; }
    for (int b = tid; b < BP; b += 256) { int c = cP[b]; oP[b] = c ? atomicAdd(&curP[b], c) : 0; }
    // ---- T side: scan, scatter to LDS, stream out ----
    sc[tid]       = (tid < BT) ? cT[tid] : 0;
    sc[tid + 256] = (tid + 256 < BT) ? cT[tid + 256] : 0;
    __syncthreads();
    block_scan512(sc, tid);
    for (int b = tid; b < BT; b += 256) cur[b] = sc[b] - cT[b];
    __syncthreads();
#pragma unroll
    for (int k = 0; k < EPB / 256; ++k) {
        int i = e0 + k * 256 + tid;
        if (i < E) {
            int bt = ld[k] >> 8;
            int pos = atomicAdd(&cur[bt], 1);
            stage[pos] = ((unsigned)(ld[k] & 255) << LSHT) | (unsigned)ls[k];
        }
    }
    __syncthreads();
    for (int b = wave; b < BT; b += 4) {
        int cnt = cT[b], so = sc[b] - cnt, go = oT[b];
        for (int i = lane; i < cnt; i += 64) {
            int pos = go + i;
            if (pos < CAPB) binT[(size_t)b * CAPB + pos] = stage[so + i];
        }
    }
    __syncthreads();
    // ---- P side ----
    sc[tid]       = (tid < BP) ? cP[tid] : 0;
    sc[tid + 256] = (tid + 256 < BP) ? cP[tid + 256] : 0;
    __syncthreads();
    block_scan512(sc, tid);
    for (int b = tid; b < BP; b += 256) cur[b] = sc[b] - cP[b];
    __syncthreads();
#pragma unroll
    for (int k = 0; k < EPB / 256; ++k) {
        int i = e0 + k * 256 + tid;
        if (i < E) {
            int bp = ls[k] >> 9;
            int pos = atomicAdd(&cur[bp], 1);
            stage[pos] = ((unsigned)(ls[k] & 511) << LSHP) | (unsigned)ld[k];
        }
    }
    __syncthreads();
    for (int b = wave; b < BP; b += 4) {
        int cnt = cP[b], so = sc[b] - cnt, go = oP[b];
        for (int i = lane; i < cnt; i += 64) {
            int pos = go + i;
            if (pos < CAPB) binP[(size_t)b * CAPB + pos] = stage[so + i];
        }
    }
}

// ---- CSR per-bucket device body: scatter into LDS, stream out int4 -----
__device__ __forceinline__ void csr_dev(const unsigned* __restrict__ binned,
                                        const int* __restrict__ cur,
                                        int* __restrict__ start_g, int* __restrict__ cnt_g,
                                        int* __restrict__ adj,
                                        int S, int lshift, int N, int b,
                                        int* lcnt, int* lscan, int* lcur, int* adj_lds) {
    int tid = threadIdx.x;
    int base = b * CAPB;
    int n = cur[b]; if (n > CAPB) n = CAPB;
    int rowlo = b * S;
    unsigned nbmask = (1u << lshift) - 1u;

    for (int i = tid; i < S; i += 256) lcnt[i] = 0;
    __syncthreads();
    for (int i = tid; i < n; i += 256)
        atomicAdd(&lcnt[binned[base + i] >> lshift], 1);
    __syncthreads();
    for (int i = tid; i < S; i += 256) lscan[i] = lcnt[i];
    __syncthreads();
    for (int off = 1; off < S; off <<= 1) {
        int i0 = tid, i1 = tid + 256;
        int v0 = (i0 >= off) ? lscan[i0 - off] : 0;
        int v1 = (S > 256 && i1 >= off) ? lscan[i1 - off] : 0;
        __syncthreads();
        if (i0 < S) lscan[i0] += v0;
        if (S > 256 && i1 < S) lscan[i1] += v1;
        __syncthreads();
    }
    for (int r = tid; r < S; r += 256) {
        int ex = lscan[r] - lcnt[r];
        lcur[r] = ex;
        int row = rowlo + r;
        if (row < N) {
            start_g[row] = base + ex;
            cnt_g[row]   = lcnt[r];
        }
    }
    __syncthreads();
    for (int i = tid; i < n; i += 256) {
        unsigned e = binned[base + i];
        int r = e >> lshift;
        int pos = atomicAdd(&lcur[r], 1);
        adj_lds[pos] = (int)(e & nbmask);
    }
    __syncthreads();
    int n4 = n & ~3;
    for (int i = tid * 4; i < n4; i += 1024)
        *(int4*)&adj[base + i] = *(const int4*)&adj_lds[i];
    for (int i = n4 + tid; i < n; i += 256)
        adj[base + i] = adj_lds[i];
}

// ---- K_B: fused [csr-t | csr-p | layer-1 MFMA pair] --------------------
__global__ void __launch_bounds__(256) k_csr_mfma1(
    const unsigned* __restrict__ binT, const unsigned* __restrict__ binP,
    const int* __restrict__ curT, const int* __restrict__ curP,
    int* __restrict__ start_t, int* __restrict__ cnt_t, int* __restrict__ adj_t,
    int* __restrict__ start_p, int* __restrict__ cnt_p, int* __restrict__ adj_p,
    int BT, int BP, int NT_, int NP_,
    const _Float16* __restrict__ XTh, const float* __restrict__ Wt1, const float* __restrict__ Wt2,
    const float* __restrict__ bt2, _Float16* __restrict__ Aht, _Float16* __restrict__ Bth,
    const float* __restrict__ pemb, const float* __restrict__ Wp1, const float* __restrict__ Wp2,
    const float* __restrict__ bp2, _Float16* __restrict__ Ahp, _Float16* __restrict__ Bph,
    int tB, int pB) {
    __shared__ int lcnt[512], lscan[512], lcur[512];
    __shared__ int adj_lds[CAPB];
    int bi = blockIdx.x;
    if (bi < BT) {
        csr_dev(binT, curT, start_t, cnt_t, adj_t, ST, LSHT, NT_, bi, lcnt, lscan, lcur, adj_lds);
    } else if (bi < BT + BP) {
        csr_dev(binP, curP, start_p, cnt_p, adj_p, SP, LSHP, NP_, bi - BT, lcnt, lscan, lcur, adj_lds);
    } else if (bi < BT + BP + tB) {
        int wb = bi - BT - BP;
        mfma_dual_dev<1>(XTh, Wt1, Wt2, bt2, Aht, Bth, NT_, wb * 4 + (threadIdx.x >> 6), tB * 4);
    } else {
        int wb = bi - BT - BP - tB;
        mfma_dual_dev<0>(pemb, Wp1, Wp2, bp2, Ahp, Bph, NP_, wb * 4 + (threadIdx.x >> 6), pB * 4);
    }
}

// ---- weight staging: pre-swizzled per-lane MFMA B-fragments into LDS ----
// layout: frag[(tbl*8 + kh*4 + nt)*64 + lane] = 8 f16 (fragment for that lane)
__device__ __forceinline__ void stage_w_lds(half8v* ldsW,
                                            const float* __restrict__ W1,
                                            const float* __restrict__ W2, int tid) {
    for (int f = tid; f < 1024; f += 256) {
        int lane = f & 63, nt = (f >> 6) & 3, kh = (f >> 8) & 1, tbl = f >> 9;
        int m = lane & 15, quad = lane >> 4;
        const float* W = tbl ? W2 : W1;
        half8v frag;
#pragma unroll
        for (int j = 0; j < 8; ++j) {
            int k = kh * 32 + quad * 8 + j;
            frag[j] = (_Float16)W[k * 64 + nt * 16 + m];
        }
        ldsW[f] = frag;
    }
}

// ---- fused gather-mean + relu + dual GEMM (one 16-row tile per wave) ----
// Gather in MFMA A-fragment layout: lane (m,quad) owns row tile*16+m,
// feature chunks [quad*8..+7] (lo) and [32+quad*8..+7] (hi).
// 8 neighbors x 2 chunks = 16 row-loads in flight per lane (MLP).
// Then C1 = relu(mean+B) @ W1, C2 = relu(mean+B) @ W2 + b2, f16 out.
__device__ __forceinline__ void gather_gemm_dev(
    const int* __restrict__ adj, const int* __restrict__ start, const int* __restrict__ cnt,
    const _Float16* __restrict__ A, const _Float16* __restrict__ B,
    const half8v* __restrict__ ldsW, const float* __restrict__ b2,
    _Float16* __restrict__ C1, _Float16* __restrict__ C2,
    int N, int tile) {
    const int lane = threadIdx.x & 63;
    const int m = lane & 15, quad = lane >> 4;
    const int row = tile * 16 + m;

    half8v accl = {}, acch = {};
    int dg = 0;
    if (row < N) {
        int st = start[row];
        dg     = cnt[row];
        const half8v* A8 = (const half8v*)A;
        int j = 0;
        for (; j + 7 < dg; j += 8) {   // 8 neighbors x 2 chunks in flight
            int n[8];
#pragma unroll
            for (int k = 0; k < 8; ++k) n[k] = adj[st + j + k];
            half8v lv[8], hv[8];
#pragma unroll
            for (int k = 0; k < 8; ++k) {
                const half8v* rp = A8 + (size_t)n[k] * 8 + quad;
                lv[k] = rp[0];
                hv[k] = rp[4];
            }
            accl += ((lv[0] + lv[1]) + (lv[2] + lv[3])) + ((lv[4] + lv[5]) + (lv[6] + lv[7]));
            acch += ((hv[0] + hv[1]) + (hv[2] + hv[3])) + ((hv[4] + hv[5]) + (hv[6] + hv[7]));
        }
        if (j + 3 < dg) {
            int n[4];
#pragma unroll
            for (int k = 0; k < 4; ++k) n[k] = adj[st + j + k];
            half8v lv[4], hv[4];
#pragma unroll
            for (int k = 0; k < 4; ++k) {
                const half8v* rp = A8 + (size_t)n[k] * 8 + quad;
                lv[k] = rp[0];
                hv[k] = rp[4];
            }
            accl += (lv[0] + lv[1]) + (lv[2] + lv[3]);
            acch += (hv[0] + hv[1]) + (hv[2] + hv[3]);
            j += 4;
        }
        for (; j < dg; ++j) {
            const half8v* rp = A8 + (size_t)adj[st + j] * 8 + quad;
            accl += rp[0];
            acch += rp[4];
        }
    }

    f16x8 alo = {}, ahi = {};
    if (row < N) {
        float inv = 1.0f / (float)(dg > 1 ? dg : 1);
        half8v bl = __builtin_nontemporal_load(&((const half8v*)B)[(size_t)row * 8 + quad]);
        half8v bh = __builtin_nontemporal_load(&((const half8v*)B)[(size_t)row * 8 + 4 + quad]);
#pragma unroll
        for (int k = 0; k < 8; ++k) {
            float vl = fmaxf((float)accl[k] * inv + (float)bl[k], 0.f);
            float vh = fmaxf((float)acch[k] * inv + (float)bh[k], 0.f);
            alo[k] = (_Float16)vl;
            ahi[k] = (_Float16)vh;
        }
    }

#pragma unroll
    for (int nt = 0; nt < 4; ++nt) {
        f16x8 w1l = (f16x8)ldsW[(0 * 8 + 0 * 4 + nt) * 64 + lane];
        f16x8 w1h = (f16x8)ldsW[(0 * 8 + 1 * 4 + nt) * 64 + lane];
        f16x8 w2l = (f16x8)ldsW[(1 * 8 + 0 * 4 + nt) * 64 + lane];
        f16x8 w2h = (f16x8)ldsW[(1 * 8 + 1 * 4 + nt) * 64 + lane];
        f32x4 a1 = {0.f, 0.f, 0.f, 0.f}, a2 = {0.f, 0.f, 0.f, 0.f};
        a1 = MFMA16(alo, w1l, a1);
        a1 = MFMA16(ahi, w1h, a1);
        a2 = MFMA16(alo, w2l, a2);
        a2 = MFMA16(ahi, w2h, a2);
        float bb = b2[nt * 16 + m];
#pragma unroll
        for (int r = 0; r < 4; ++r) {
            int orow = tile * 16 + quad * 4 + r;
            if (orow < N) {
                C1[(size_t)orow * 64 + nt * 16 + m] = (_Float16)a1[r];
                C2[(size_t)orow * 64 + nt * 16 + m] = (_Float16)(a2[r] + bb);
            }
        }
    }
}

// ---- K_CD: fused [layer-1 gather+relu+layer-2 dual GEMM], t | p --------
__global__ void __launch_bounds__(256) k_gather_gemm(
    const int* __restrict__ adjT, const int* __restrict__ startT, const int* __restrict__ cntT,
    const _Float16* __restrict__ At, const _Float16* __restrict__ Bt,
    const float* __restrict__ Wt1, const float* __restrict__ Wt2, const float* __restrict__ bt2,
    _Float16* __restrict__ C1t, _Float16* __restrict__ C2t, int NT_,
    const int* __restrict__ adjP, const int* __restrict__ startP, const int* __restrict__ cntP,
    const _Float16* __restrict__ Ap, const _Float16* __restrict__ Bp,
    const float* __restrict__ Wp1, const float* __restrict__ Wp2, const float* __restrict__ bp2,
    _Float16* __restrict__ C1p, _Float16* __restrict__ C2p, int NP_,
    int tTB) {
    __shared__ half8v ldsW[1024];  // 16 KiB: pre-swizzled weight fragments
    const int tid = threadIdx.x, wave = tid >> 6;
    if ((int)blockIdx.x < tTB) {
        stage_w_lds(ldsW, Wt1, Wt2, tid);
        __syncthreads();
        int tile = blockIdx.x * 4 + wave;
        if (tile < ((NT_ + 15) >> 4))
            gather_gemm_dev(adjT, startT, cntT, At, Bt, ldsW, bt2, C1t, C2t, NT_, tile);
    } else {
        stage_w_lds(ldsW, Wp1, Wp2, tid);
        __syncthreads();
        int tile = (blockIdx.x - tTB) * 4 + wave;
        if (tile < ((NP_ + 15) >> 4))
            gather_gemm_dev(adjP, startP, cntP, Ap, Bp, ldsW, bp2, C1p, C2p, NP_, tile);
    }
}

// ---- gather-mean device body: 8 lanes/row, 16 loads in flight ----------
// Output is consumed RANDOMLY by dot_h -> regular cached store (keep in L2/LLC).
__device__ __forceinline__ void gather_dev(
    const int* __restrict__ adj, const int* __restrict__ start, const int* __restrict__ cnt,
    const _Float16* __restrict__ A, const _Float16* __restrict__ B,
    _Float16* __restrict__ out, int do_relu, int N, int gidx) {
    int row = gidx >> 3;
    int c   = gidx & 7;
    if (row >= N) return;

    int st = start[row];
    int dg = cnt[row];
    const half8v* A8 = (const half8v*)A;
    half8v acc = {};
    int j = 0;
    for (; j + 15 < dg; j += 16) {  // 16 gathers in flight
        int n[16];
#pragma unroll
        for (int k = 0; k < 16; ++k) n[k] = adj[st + j + k];
        half8v v[16];
#pragma unroll
        for (int k = 0; k < 16; ++k) v[k] = A8[(size_t)n[k] * 8 + c];
        half8v s0 = ((v[0] + v[1]) + (v[2] + v[3])) + ((v[4] + v[5]) + (v[6] + v[7]));
        half8v s1 = ((v[8] + v[9]) + (v[10] + v[11])) + ((v[12] + v[13]) + (v[14] + v[15]));
        acc += s0 + s1;
    }
    if (j + 7 < dg) {
        int n[8];
#pragma unroll
        for (int k = 0; k < 8; ++k) n[k] = adj[st + j + k];
        half8v v[8];
#pragma unroll
        for (int k = 0; k < 8; ++k) v[k] = A8[(size_t)n[k] * 8 + c];
        acc += ((v[0] + v[1]) + (v[2] + v[3])) + ((v[4] + v[5]) + (v[6] + v[7]));
        j += 8;
    }
    if (j + 3 < dg) {
        int n[4];
#pragma unroll
        for (int k = 0; k < 4; ++k) n[k] = adj[st + j + k];
        half8v v[4];
#pragma unroll
        for (int k = 0; k < 4; ++k) v[k] = A8[(size_t)n[k] * 8 + c];
        acc += (v[0] + v[1]) + (v[2] + v[3]);
        j += 4;
    }
    for (; j < dg; ++j)
        acc += A8[(size_t)adj[st + j] * 8 + c];

    float inv = 1.0f / (float)(dg > 1 ? dg : 1);
    half8v b8 = __builtin_nontemporal_load(&((const half8v*)B)[(size_t)row * 8 + c]);
    half8v o;
#pragma unroll
    for (int k = 0; k < 8; ++k) {
        float v = (float)acc[k] * inv + (float)b8[k];
        if (do_relu) v = fmaxf(v, 0.f);
        o[k] = (_Float16)v;
    }
    ((half8v*)out)[(size_t)row * 8 + c] = o;
}

// ---- K_E: fused [gather-t | gather-p] ----------------------------------
__global__ void __launch_bounds__(256) k_gather2(
    const int* __restrict__ adjT, const int* __restrict__ startT, const int* __restrict__ cntT,
    const _Float16* __restrict__ At, const _Float16* __restrict__ Bt, _Float16* __restrict__ outT, int NT_,
    const int* __restrict__ adjP, const int* __restrict__ startP, const int* __restrict__ cntP,
    const _Float16* __restrict__ Ap, const _Float16* __restrict__ Bp, _Float16* __restrict__ outP, int NP_,
    int do_relu, int wTb) {
    if ((int)blockIdx.x < wTb)
        gather_dev(adjT, startT, cntT, At, Bt, outT, do_relu, NT_, blockIdx.x * 256 + threadIdx.x);
    else
        gather_dev(adjP, startP, cntP, Ap, Bp, outP, do_relu, NP_,
                   (blockIdx.x - wTb) * 256 + threadIdx.x);
}

// ---- classifier: 8 lanes/edge, v_dot2_f32_f16 --------------------------
__global__ void __launch_bounds__(256) dot_h(const _Float16* __restrict__ p2,
                                             const _Float16* __restrict__ t2,
                                             const int* __restrict__ els,
                                             const int* __restrict__ eld,
                                             float* __restrict__ out, int EL) {
    int tid = blockIdx.x * 256 + threadIdx.x;
    int i = tid >> 3, c = tid & 7;
    if (i < EL) {
        int s = __builtin_nontemporal_load(&els[i]);
        int d = __builtin_nontemporal_load(&eld[i]);
        half8v a = ((const half8v*)p2)[(size_t)s * 8 + c];
        half8v b = ((const half8v*)t2)[(size_t)d * 8 + c];
        float v = 0.f;
#ifdef HAS_FDOT2
        const half2v* ap = (const half2v*)&a;
        const half2v* bp = (const half2v*)&b;
#pragma unroll
        for (int k = 0; k < 4; ++k) v = __builtin_amdgcn_fdot2(ap[k], bp[k], v, false);
#else
#pragma unroll
        for (int k = 0; k < 8; ++k) v += (float)a[k] * (float)b[k];
#endif
        v += __shfl_xor(v, 1, 64);
        v += __shfl_xor(v, 2, 64);
        v += __shfl_xor(v, 4, 64);
        if (c == 0) __builtin_nontemporal_store(v, &out[i]);
    }
}

extern "C" void kernel_launch(void* const* d_in, const int* in_sizes, int n_in,
                              void* d_out, int out_size, void* d_ws, size_t ws_size,
                              hipStream_t stream) {
    const float* x_taxon  = (const float*)d_in[0];
    const float* tlw      = (const float*)d_in[1];
    const float* tlb      = (const float*)d_in[2];
    const float* pemb     = (const float*)d_in[3];
    const float* temb     = (const float*)d_in[4];
    const int*   edge_src = (const int*)d_in[7];
    const int*   edge_dst = (const int*)d_in[8];
    const int*   el_src   = (const int*)d_in[9];
    const int*   el_dst   = (const int*)d_in[10];
    const float* c1pt_wl  = (const float*)d_in[11];
    const float* c1pt_wr  = (const float*)d_in[12];
    const float* c1tp_wl  = (const float*)d_in[13];
    const float* c1tp_wr  = (const float*)d_in[14];
    const float* c2pt_wl  = (const float*)d_in[15];
    const float* c2pt_wr  = (const float*)d_in[16];
    const float* c2tp_wl  = (const float*)d_in[17];
    const float* c2tp_wr  = (const float*)d_in[18];
    const float* c1pt_bl  = (const float*)d_in[19];
    const float* c1tp_bl  = (const float*)d_in[20];
    const float* c2pt_bl  = (const float*)d_in[21];
    const float* c2tp_bl  = (const float*)d_in[22];

    const int NP_ = in_sizes[5];
    const int NT_ = in_sizes[6];
    const int E_  = in_sizes[7];
    const int EL_ = in_sizes[9];
    const int BT  = (NT_ + ST - 1) / ST;   // 391
    const int BP  = (NP_ + SP - 1) / SP;   // 391

    // workspace (same 4*NT + 4*NP f16-row footprint as before):
    //   XTh  [NT]: K_A out, K_B in; then Aht2 alias (K_CD out, K_E in)
    //   Aht1 [NT]: K_B out, K_CD p-gather table; then T2h alias (K_E out)
    //   Bth1 [NT]: K_B out, K_CD t-addend
    //   Bth2 [NT]: K_CD out, K_E t-addend
    //   Ahp1 [NP]: K_B out, K_CD t-gather table; then P2h alias (K_E out)
    //   Bph1 [NP]: K_B out, K_CD p-addend
    //   Ahp2 [NP]: K_CD out, K_E t-gather table
    //   Bph2 [NP]: K_CD out, K_E p-addend
    _Float16* hb   = (_Float16*)d_ws;
    _Float16* XTh  = hb;
    _Float16* Aht1 = XTh + (size_t)NT_ * H;
    _Float16* Bth1 = Aht1 + (size_t)NT_ * H;
    _Float16* Bth2 = Bth1 + (size_t)NT_ * H;
    _Float16* Ahp1 = Bth2 + (size_t)NT_ * H;
    _Float16* Bph1 = Ahp1 + (size_t)NP_ * H;
    _Float16* Ahp2 = Bph1 + (size_t)NP_ * H;
    _Float16* Bph2 = Ahp2 + (size_t)NP_ * H;
    _Float16* Aht2 = XTh;    // alias: XTh dead after K_B
    _Float16* T2h  = Aht1;   // alias: Aht1 dead after K_CD
    _Float16* P2h  = Ahp1;   // alias: Ahp1 dead after K_CD

    unsigned* binT    = (unsigned*)(Bph2 + (size_t)NP_ * H);  // BT*CAPB
    unsigned* binP    = binT + (size_t)BT * CAPB;             // BP*CAPB
    int*      adj_t   = (int*)(binP + (size_t)BP * CAPB);     // BT*CAPB
    int*      adj_p   = adj_t + (size_t)BT * CAPB;            // BP*CAPB
    int* start_t = adj_p + (size_t)BP * CAPB;  // NT
    int* start_p = start_t + NT_;              // NP
    int* cnt_t   = start_p + NP_;              // NT
    int* cnt_p   = cnt_t + NT_;                // NP
    int* curT    = cnt_p + NP_;                // BMAX
    int* curP    = curT + BMAX;                // BMAX

    (void)hipMemsetAsync(curT, 0, 2 * BMAX * sizeof(int), stream);

    const int nbBin = (E_ + EPB - 1) / EPB;              // 489
    const int XTB   = 512;                               // xt GEMM blocks
    const int wT = (NT_ * 8 + 255) / 256, wP = (NP_ * 8 + 255) / 256;
    const int tB = 256, pB = 512;                        // MFMA pair split (tiles 1:2)

    // K_A: bin (blocks 0..nbBin, dispatched first => owns the CUs early) + xt GEMM
    k_bin_xt<<<nbBin + XTB, 256, 0, stream>>>(
        edge_src, edge_dst, curT, curP, binT, binP, BT, BP, E_, nbBin,
        x_taxon, tlw, tlb, temb, XTh, NT_, XTB);

    // K_B: csr-t + csr-p + layer-1 MFMA pair
    //   Aht1 = XT@c1tp_wl, Bth1 = XT@c1pt_wr + c1pt_bl
    //   Ahp1 = pemb@c1pt_wl, Bph1 = pemb@c1tp_wr + c1tp_bl
    k_csr_mfma1<<<BT + BP + tB + pB, 256, 0, stream>>>(
        binT, binP, curT, curP,
        start_t, cnt_t, adj_t, start_p, cnt_p, adj_p, BT, BP, NT_, NP_,
        XTh, c1tp_wl, c1pt_wr, c1pt_bl, Aht1, Bth1,
        pemb, c1pt_wl, c1tp_wr, c1tp_bl, Ahp1, Bph1, tB, pB);

    // K_CD: fused layer-1 gather (+relu) + layer-2 dual GEMM
    //   t: t1 = relu(mean(Ahp1)+Bth1); Aht2 = t1@c2tp_wl; Bth2 = t1@c2pt_wr + c2pt_bl
    //   p: p1 = relu(mean(Aht1)+Bph1); Ahp2 = p1@c2pt_wl; Bph2 = p1@c2tp_wr + c2tp_bl
    const int tTB = (((NT_ + 15) >> 4) + 3) >> 2;
    const int pTB = (((NP_ + 15) >> 4) + 3) >> 2;
    k_gather_gemm<<<tTB + pTB, 256, 0, stream>>>(
        adj_t, start_t, cnt_t, Ahp1, Bth1, c2tp_wl, c2pt_wr, c2pt_bl, Aht2, Bth2, NT_,
        adj_p, start_p, cnt_p, Aht1, Bph1, c2pt_wl, c2tp_wr, c2tp_bl, Ahp2, Bph2, NP_,
        tTB);

    // K_E: layer-2 gathers (no relu)
    //   t2 = mean(Ahp2)+Bth2 -> T2h ; p2 = mean(Aht2)+Bph2 -> P2h
    k_gather2<<<wT + wP, 256, 0, stream>>>(
        adj_t, start_t, cnt_t, Ahp2, Bth2, T2h, NT_,
        adj_p, start_p, cnt_p, Aht2, Bph2, P2h, NP_, 0, wT);

    // classifier
    dot_h<<<(EL_ * 8 + 255) / 256, 256, 0, stream>>>(P2h, T2h, el_src, el_dst,
                                                     (float*)d_out, EL_);
}

// Round 7
// 460.280 us; speedup vs baseline: 1.0967x; 1.0358x over previous
//
#include <hip/hip_runtime.h>

#define H 64
#define EPB 4096        // edges per bin block (489 blocks)
#define BMAX 400        // >= bucket count (391)
#define ST 256          // taxon rows per bucket
#define SP 512          // palmprint rows per bucket
#define LSHT 18         // t-entry: (dst&255)<<18 | src
#define LSHP 17         // p-entry: (src&511)<<17 | dst
#define CAPB 5632       // bucket capacity (mean 5120 + 7 sigma); %4==0

typedef _Float16 half2v __attribute__((ext_vector_type(2)));
typedef _Float16 half8v __attribute__((ext_vector_type(8)));
typedef _Float16 f16x8  __attribute__((ext_vector_type(8)));
typedef float    f32x4  __attribute__((ext_vector_type(4)));
typedef int      i32x4  __attribute__((ext_vector_type(4)));

#if defined(__has_builtin)
#if __has_builtin(__builtin_amdgcn_fdot2)
#define HAS_FDOT2 1
#endif
#endif

#define MFMA16(a, b, c) __builtin_amdgcn_mfma_f32_16x16x32_f16(a, b, c, 0, 0, 0)

// ---- MFMA dual GEMM device body: C1 = A@W1, C2 = A@W2 + b2 (f16 out) ----
template <int HALF_IN>
__device__ __forceinline__ void mfma_dual_dev(const void* __restrict__ Av,
                                              const float* __restrict__ W1,
                                              const float* __restrict__ W2,
                                              const float* __restrict__ b2,
                                              _Float16* __restrict__ C1,
                                              _Float16* __restrict__ C2,
                                              int N, int wid, int nwaves) {
    const int lane = threadIdx.x & 63;
    const int m = lane & 15, quad = lane >> 4;
    const int nTiles = (N + 15) >> 4;

    f16x8 w1f[2][4], w2f[2][4];
#pragma unroll
    for (int kh = 0; kh < 2; ++kh)
#pragma unroll
        for (int nt = 0; nt < 4; ++nt) {
            f16x8 a, b;
#pragma unroll
            for (int j = 0; j < 8; ++j) {
                int k = kh * 32 + quad * 8 + j;
                a[j] = (_Float16)W1[k * 64 + nt * 16 + m];
                b[j] = (_Float16)W2[k * 64 + nt * 16 + m];
            }
            w1f[kh][nt] = a;
            w2f[kh][nt] = b;
        }
    float bv[4];
#pragma unroll
    for (int nt = 0; nt < 4; ++nt) bv[nt] = b2[nt * 16 + m];

    for (int t = wid; t < nTiles; t += nwaves) {
        int row = t * 16 + m;
        f16x8 alo = {}, ahi = {};
        if (row < N) {
            if (HALF_IN) {
                const f16x8* A8 = (const f16x8*)Av;
                alo = __builtin_nontemporal_load(A8 + (size_t)row * 8 + quad);
                ahi = __builtin_nontemporal_load(A8 + (size_t)row * 8 + 4 + quad);
            } else {
                const f32x4* p = (const f32x4*)((const float*)Av + (size_t)row * 64);
                f32x4 x0 = __builtin_nontemporal_load(p + quad * 2);
                f32x4 x1 = __builtin_nontemporal_load(p + quad * 2 + 1);
                f32x4 x2 = __builtin_nontemporal_load(p + 8 + quad * 2);
                f32x4 x3 = __builtin_nontemporal_load(p + 8 + quad * 2 + 1);
                alo[0] = (_Float16)x0[0]; alo[1] = (_Float16)x0[1];
                alo[2] = (_Float16)x0[2]; alo[3] = (_Float16)x0[3];
                alo[4] = (_Float16)x1[0]; alo[5] = (_Float16)x1[1];
                alo[6] = (_Float16)x1[2]; alo[7] = (_Float16)x1[3];
                ahi[0] = (_Float16)x2[0]; ahi[1] = (_Float16)x2[1];
                ahi[2] = (_Float16)x2[2]; ahi[3] = (_Float16)x2[3];
                ahi[4] = (_Float16)x3[0]; ahi[5] = (_Float16)x3[1];
                ahi[6] = (_Float16)x3[2]; ahi[7] = (_Float16)x3[3];
            }
        }
#pragma unroll
        for (int nt = 0; nt < 4; ++nt) {
            f32x4 a1 = {0.f, 0.f, 0.f, 0.f}, a2 = {0.f, 0.f, 0.f, 0.f};
            a1 = MFMA16(alo, w1f[0][nt], a1);
            a1 = MFMA16(ahi, w1f[1][nt], a1);
            a2 = MFMA16(alo, w2f[0][nt], a2);
            a2 = MFMA16(ahi, w2f[1][nt], a2);
#pragma unroll
            for (int r = 0; r < 4; ++r) {
                int orow = t * 16 + quad * 4 + r;
                if (orow < N) {
                    C1[(size_t)orow * 64 + nt * 16 + m] = (_Float16)a1[r];
                    C2[(size_t)orow * 64 + nt * 16 + m] = (_Float16)(a2[r] + bv[nt]);
                }
            }
        }
    }
}

// ---- MFMA xt device body: C = A(f32)@W + bias + addend(f32), f16 out ----
__device__ __forceinline__ void mfma_xt_dev(const float* __restrict__ A,
                                            const float* __restrict__ W,
                                            const float* __restrict__ bias,
                                            const float* __restrict__ addend,
                                            _Float16* __restrict__ C,
                                            int N, int wid, int nwaves) {
    const int lane = threadIdx.x & 63;
    const int m = lane & 15, quad = lane >> 4;
    const int nTiles = (N + 15) >> 4;

    f16x8 wf[2][4];
#pragma unroll
    for (int kh = 0; kh < 2; ++kh)
#pragma unroll
        for (int nt = 0; nt < 4; ++nt) {
            f16x8 a;
#pragma unroll
            for (int j = 0; j < 8; ++j) {
                int k = kh * 32 + quad * 8 + j;
                a[j] = (_Float16)W[k * 64 + nt * 16 + m];
            }
            wf[kh][nt] = a;
        }
    float bv[4];
#pragma unroll
    for (int nt = 0; nt < 4; ++nt) bv[nt] = bias[nt * 16 + m];

    for (int t = wid; t < nTiles; t += nwaves) {
        int row = t * 16 + m;
        f16x8 alo = {}, ahi = {};
        if (row < N) {
            const f32x4* p = (const f32x4*)(A + (size_t)row * 64);
            f32x4 x0 = __builtin_nontemporal_load(p + quad * 2);
            f32x4 x1 = __builtin_nontemporal_load(p + quad * 2 + 1);
            f32x4 x2 = __builtin_nontemporal_load(p + 8 + quad * 2);
            f32x4 x3 = __builtin_nontemporal_load(p + 8 + quad * 2 + 1);
            alo[0] = (_Float16)x0[0]; alo[1] = (_Float16)x0[1];
            alo[2] = (_Float16)x0[2]; alo[3] = (_Float16)x0[3];
            alo[4] = (_Float16)x1[0]; alo[5] = (_Float16)x1[1];
            alo[6] = (_Float16)x1[2]; alo[7] = (_Float16)x1[3];
            ahi[0] = (_Float16)x2[0]; ahi[1] = (_Float16)x2[1];
            ahi[2] = (_Float16)x2[2]; ahi[3] = (_Float16)x2[3];
            ahi[4] = (_Float16)x3[0]; ahi[5] = (_Float16)x3[1];
            ahi[6] = (_Float16)x3[2]; ahi[7] = (_Float16)x3[3];
        }
#pragma unroll
        for (int nt = 0; nt < 4; ++nt) {
            f32x4 a1 = {0.f, 0.f, 0.f, 0.f};
            a1 = MFMA16(alo, wf[0][nt], a1);
            a1 = MFMA16(ahi, wf[1][nt], a1);
#pragma unroll
            for (int r = 0; r < 4; ++r) {
                int orow = t * 16 + quad * 4 + r;
                if (orow < N) {
                    float ad = __builtin_nontemporal_load(
                        &addend[(size_t)orow * 64 + nt * 16 + m]);
                    C[(size_t)orow * 64 + nt * 16 + m] = (_Float16)(a1[r] + bv[nt] + ad);
                }
            }
        }
    }
}

// in-place inclusive scan over sc[0..511] (counts pre-loaded), 256 threads
__device__ __forceinline__ void block_scan512(int* sc, int tid) {
    for (int off = 1; off < 512; off <<= 1) {
        int i0 = tid, i1 = tid + 256;
        int v0 = (i0 >= off) ? sc[i0 - off] : 0;
        int v1 = (i1 >= off) ? sc[i1 - off] : 0;
        __syncthreads();
        sc[i0] += v0;
        sc[i1] += v1;
        __syncthreads();
    }
}

// ---- K_A: fused [bin (LDS sort-then-stream) | xt GEMM] -----------------
__global__ void __launch_bounds__(256) k_bin_xt(
    const int* __restrict__ src, const int* __restrict__ dst,
    int* __restrict__ curT, int* __restrict__ curP,
    unsigned* __restrict__ binT, unsigned* __restrict__ binP,
    int BT, int BP, int E, int nbBin,
    const float* __restrict__ A, const float* __restrict__ W,
    const float* __restrict__ bias, const float* __restrict__ addend,
    _Float16* __restrict__ C, int NT_, int xtBlocks) {
    __shared__ int cT[BMAX], cP[BMAX], oT[BMAX], oP[BMAX], cur[BMAX];
    __shared__ int sc[512];
    __shared__ unsigned stage[EPB];
    int tid = threadIdx.x;
    if ((int)blockIdx.x >= nbBin) {
        int xb = blockIdx.x - nbBin;
        mfma_xt_dev(A, W, bias, addend, C, NT_, xb * 4 + (tid >> 6), xtBlocks * 4);
        return;
    }
    const int wave = tid >> 6, lane = tid & 63;
    for (int i = tid; i < BMAX; i += 256) { cT[i] = 0; cP[i] = 0; }
    __syncthreads();
    int e0 = blockIdx.x * EPB;
    int ls[EPB / 256], ld[EPB / 256];
#pragma unroll
    for (int k = 0; k < EPB / 256; ++k) {
        int i = e0 + k * 256 + tid;
        if (i < E) {
            ls[k] = __builtin_nontemporal_load(&src[i]);
            ld[k] = __builtin_nontemporal_load(&dst[i]);
            atomicAdd(&cT[ld[k] >> 8], 1);
            atomicAdd(&cP[ls[k] >> 9], 1);
        }
    }
    __syncthreads();
    // grab global chunks
    for (int b = tid; b < BT; b += 256) { int c = cT[b]; oT[b] = c ? atomicAdd(&curT[b], c) : 0; }
    for (int b = tid; b < BP; b += 256) { int c = cP[b]; oP[b] = c ? atomicAdd(&curP[b], c) : 0; }
    // ---- T side: scan, scatter to LDS, stream out ----
    sc[tid]       = (tid < BT) ? cT[tid] : 0;
    sc[tid + 256] = (tid + 256 < BT) ? cT[tid + 256] : 0;
    __syncthreads();
    block_scan512(sc, tid);
    for (int b = tid; b < BT; b += 256) cur[b] = sc[b] - cT[b];
    __syncthreads();
#pragma unroll
    for (int k = 0; k < EPB / 256; ++k) {
        int i = e0 + k * 256 + tid;
        if (i < E) {
            int bt = ld[k] >> 8;
            int pos = atomicAdd(&cur[bt], 1);
            stage[pos] = ((unsigned)(ld[k] & 255) << LSHT) | (unsigned)ls[k];
        }
    }
    __syncthreads();
    for (int b = wave; b < BT; b += 4) {
        int cnt = cT[b], so = sc[b] - cnt, go = oT[b];
        for (int i = lane; i < cnt; i += 64) {
            int pos = go + i;
            if (pos < CAPB) binT[(size_t)b * CAPB + pos] = stage[so + i];
        }
    }
    __syncthreads();
    // ---- P side ----
    sc[tid]       = (tid < BP) ? cP[tid] : 0;
    sc[tid + 256] = (tid + 256 < BP) ? cP[tid + 256] : 0;
    __syncthreads();
    block_scan512(sc, tid);
    for (int b = tid; b < BP; b += 256) cur[b] = sc[b] - cP[b];
    __syncthreads();
#pragma unroll
    for (int k = 0; k < EPB / 256; ++k) {
        int i = e0 + k * 256 + tid;
        if (i < E) {
            int bp = ls[k] >> 9;
            int pos = atomicAdd(&cur[bp], 1);
            stage[pos] = ((unsigned)(ls[k] & 511) << LSHP) | (unsigned)ld[k];
        }
    }
    __syncthreads();
    for (int b = wave; b < BP; b += 4) {
        int cnt = cP[b], so = sc[b] - cnt, go = oP[b];
        for (int i = lane; i < cnt; i += 64) {
            int pos = go + i;
            if (pos < CAPB) binP[(size_t)b * CAPB + pos] = stage[so + i];
        }
    }
}

// ---- CSR per-bucket device body: scatter into LDS, stream out int4 -----
__device__ __forceinline__ void csr_dev(const unsigned* __restrict__ binned,
                                        const int* __restrict__ cur,
                                        int* __restrict__ start_g, int* __restrict__ cnt_g,
                                        int* __restrict__ adj,
                                        int S, int lshift, int N, int b,
                                        int* lcnt, int* lscan, int* lcur, int* adj_lds) {
    int tid = threadIdx.x;
    int base = b * CAPB;
    int n = cur[b]; if (n > CAPB) n = CAPB;
    int rowlo = b * S;
    unsigned nbmask = (1u << lshift) - 1u;

    for (int i = tid; i < S; i += 256) lcnt[i] = 0;
    __syncthreads();
    for (int i = tid; i < n; i += 256)
        atomicAdd(&lcnt[binned[base + i] >> lshift], 1);
    __syncthreads();
    for (int i = tid; i < S; i += 256) lscan[i] = lcnt[i];
    __syncthreads();
    for (int off = 1; off < S; off <<= 1) {
        int i0 = tid, i1 = tid + 256;
        int v0 = (i0 >= off) ? lscan[i0 - off] : 0;
        int v1 = (S > 256 && i1 >= off) ? lscan[i1 - off] : 0;
        __syncthreads();
        if (i0 < S) lscan[i0] += v0;
        if (S > 256 && i1 < S) lscan[i1] += v1;
        __syncthreads();
    }
    for (int r = tid; r < S; r += 256) {
        int ex = lscan[r] - lcnt[r];
        lcur[r] = ex;
        int row = rowlo + r;
        if (row < N) {
            start_g[row] = base + ex;
            cnt_g[row]   = lcnt[r];
        }
    }
    __syncthreads();
    for (int i = tid; i < n; i += 256) {
        unsigned e = binned[base + i];
        int r = e >> lshift;
        int pos = atomicAdd(&lcur[r], 1);
        adj_lds[pos] = (int)(e & nbmask);
    }
    __syncthreads();
    int n4 = n & ~3;
    for (int i = tid * 4; i < n4; i += 1024)
        *(int4*)&adj[base + i] = *(const int4*)&adj_lds[i];
    for (int i = n4 + tid; i < n; i += 256)
        adj[base + i] = adj_lds[i];
}

// ---- K_B: fused [csr-t | csr-p | layer-1 MFMA pair] --------------------
__global__ void __launch_bounds__(256) k_csr_mfma1(
    const unsigned* __restrict__ binT, const unsigned* __restrict__ binP,
    const int* __restrict__ curT, const int* __restrict__ curP,
    int* __restrict__ start_t, int* __restrict__ cnt_t, int* __restrict__ adj_t,
    int* __restrict__ start_p, int* __restrict__ cnt_p, int* __restrict__ adj_p,
    int BT, int BP, int NT_, int NP_,
    const _Float16* __restrict__ XTh, const float* __restrict__ Wt1, const float* __restrict__ Wt2,
    const float* __restrict__ bt2, _Float16* __restrict__ Aht, _Float16* __restrict__ Bth,
    const float* __restrict__ pemb, const float* __restrict__ Wp1, const float* __restrict__ Wp2,
    const float* __restrict__ bp2, _Float16* __restrict__ Ahp, _Float16* __restrict__ Bph,
    int tB, int pB) {
    __shared__ int lcnt[512], lscan[512], lcur[512];
    __shared__ int adj_lds[CAPB];
    int bi = blockIdx.x;
    if (bi < BT) {
        csr_dev(binT, curT, start_t, cnt_t, adj_t, ST, LSHT, NT_, bi, lcnt, lscan, lcur, adj_lds);
    } else if (bi < BT + BP) {
        csr_dev(binP, curP, start_p, cnt_p, adj_p, SP, LSHP, NP_, bi - BT, lcnt, lscan, lcur, adj_lds);
    } else if (bi < BT + BP + tB) {
        int wb = bi - BT - BP;
        mfma_dual_dev<1>(XTh, Wt1, Wt2, bt2, Aht, Bth, NT_, wb * 4 + (threadIdx.x >> 6), tB * 4);
    } else {
        int wb = bi - BT - BP - tB;
        mfma_dual_dev<0>(pemb, Wp1, Wp2, bp2, Ahp, Bph, NP_, wb * 4 + (threadIdx.x >> 6), pB * 4);
    }
}

// ---- weight staging: pre-swizzled per-lane MFMA B-fragments into LDS ----
// layout: frag[(tbl*8 + kh*4 + nt)*64 + lane] = 8 f16 (fragment for that lane)
__device__ __forceinline__ void stage_w_lds(half8v* ldsW,
                                            const float* __restrict__ W1,
                                            const float* __restrict__ W2, int tid) {
    for (int f = tid; f < 1024; f += 256) {
        int lane = f & 63, nt = (f >> 6) & 3, kh = (f >> 8) & 1, tbl = f >> 9;
        int m = lane & 15, quad = lane >> 4;
        const float* W = tbl ? W2 : W1;
        half8v frag;
#pragma unroll
        for (int j = 0; j < 8; ++j) {
            int k = kh * 32 + quad * 8 + j;
            frag[j] = (_Float16)W[k * 64 + nt * 16 + m];
        }
        ldsW[f] = frag;
    }
}

// ---- fused gather-mean + relu + dual GEMM (one 16-row tile per wave) ----
// Gather in MFMA A-fragment layout; epilogue stages the 16x64 f16 output
// tiles in per-wave LDS (144B row stride) and writes coalesced f16x8 full
// lines (kills write-allocate FETCH + partial-sector WRITE amplification).
#define LDSC_STRIDE 72   // halves per row (144 B)
#define LDSC_TBL    1152 // halves per table (16 rows)
__device__ __forceinline__ void gather_gemm_dev(
    const int* __restrict__ adj, const int* __restrict__ start, const int* __restrict__ cnt,
    const _Float16* __restrict__ A, const _Float16* __restrict__ B,
    const half8v* __restrict__ ldsW, _Float16* __restrict__ ldsC_w,
    const float* __restrict__ b2,
    _Float16* __restrict__ C1, _Float16* __restrict__ C2,
    int N, int tile) {
    const int lane = threadIdx.x & 63;
    const int m = lane & 15, quad = lane >> 4;
    const int row = tile * 16 + m;

    half8v accl = {}, acch = {};
    int dg = 0;
    if (row < N) {
        int st = start[row];
        dg     = cnt[row];
        const half8v* A8 = (const half8v*)A;
        int j = 0;
        for (; j + 7 < dg; j += 8) {   // 8 neighbors x 2 chunks in flight
            int n[8];
#pragma unroll
            for (int k = 0; k < 8; ++k) n[k] = adj[st + j + k];
            half8v lv[8], hv[8];
#pragma unroll
            for (int k = 0; k < 8; ++k) {
                const half8v* rp = A8 + (size_t)n[k] * 8 + quad;
                lv[k] = rp[0];
                hv[k] = rp[4];
            }
            accl += ((lv[0] + lv[1]) + (lv[2] + lv[3])) + ((lv[4] + lv[5]) + (lv[6] + lv[7]));
            acch += ((hv[0] + hv[1]) + (hv[2] + hv[3])) + ((hv[4] + hv[5]) + (hv[6] + hv[7]));
        }
        if (j + 3 < dg) {
            int n[4];
#pragma unroll
            for (int k = 0; k < 4; ++k) n[k] = adj[st + j + k];
            half8v lv[4], hv[4];
#pragma unroll
            for (int k = 0; k < 4; ++k) {
                const half8v* rp = A8 + (size_t)n[k] * 8 + quad;
                lv[k] = rp[0];
                hv[k] = rp[4];
            }
            accl += (lv[0] + lv[1]) + (lv[2] + lv[3]);
            acch += (hv[0] + hv[1]) + (hv[2] + hv[3]);
            j += 4;
        }
        for (; j < dg; ++j) {
            const half8v* rp = A8 + (size_t)adj[st + j] * 8 + quad;
            accl += rp[0];
            acch += rp[4];
        }
    }

    f16x8 alo = {}, ahi = {};
    if (row < N) {
        float inv = 1.0f / (float)(dg > 1 ? dg : 1);
        half8v bl = __builtin_nontemporal_load(&((const half8v*)B)[(size_t)row * 8 + quad]);
        half8v bh = __builtin_nontemporal_load(&((const half8v*)B)[(size_t)row * 8 + 4 + quad]);
#pragma unroll
        for (int k = 0; k < 8; ++k) {
            float vl = fmaxf((float)accl[k] * inv + (float)bl[k], 0.f);
            float vh = fmaxf((float)acch[k] * inv + (float)bh[k], 0.f);
            alo[k] = (_Float16)vl;
            ahi[k] = (_Float16)vh;
        }
    }

#pragma unroll
    for (int nt = 0; nt < 4; ++nt) {
        f16x8 w1l = (f16x8)ldsW[(0 * 8 + 0 * 4 + nt) * 64 + lane];
        f16x8 w1h = (f16x8)ldsW[(0 * 8 + 1 * 4 + nt) * 64 + lane];
        f16x8 w2l = (f16x8)ldsW[(1 * 8 + 0 * 4 + nt) * 64 + lane];
        f16x8 w2h = (f16x8)ldsW[(1 * 8 + 1 * 4 + nt) * 64 + lane];
        f32x4 a1 = {0.f, 0.f, 0.f, 0.f}, a2 = {0.f, 0.f, 0.f, 0.f};
        a1 = MFMA16(alo, w1l, a1);
        a1 = MFMA16(ahi, w1h, a1);
        a2 = MFMA16(alo, w2l, a2);
        a2 = MFMA16(ahi, w2h, a2);
        float bb = b2[nt * 16 + m];
#pragma unroll
        for (int r = 0; r < 4; ++r) {
            int lr = quad * 4 + r;  // local tile row 0..15
            ldsC_w[0 * LDSC_TBL + lr * LDSC_STRIDE + nt * 16 + m] = (_Float16)a1[r];
            ldsC_w[1 * LDSC_TBL + lr * LDSC_STRIDE + nt * 16 + m] = (_Float16)(a2[r] + bb);
        }
    }

    // coalesced store: lane -> (row = lane>>2, 16B chunk = lane&3), 2 halves
    {
        int rl = lane >> 2, ch = lane & 3;
        int orow = tile * 16 + rl;
        if (orow < N) {
#pragma unroll
            for (int half = 0; half < 2; ++half) {
                int lo = rl * LDSC_STRIDE + ch * 8 + half * 32;
                f16x8 v1 = *(const f16x8*)&ldsC_w[0 * LDSC_TBL + lo];
                f16x8 v2 = *(const f16x8*)&ldsC_w[1 * LDSC_TBL + lo];
                size_t go = (size_t)orow * 64 + ch * 8 + half * 32;
                *(f16x8*)&C1[go] = v1;
                *(f16x8*)&C2[go] = v2;
            }
        }
    }
}

// ---- K_CD: fused [layer-1 gather+relu+layer-2 dual GEMM], t | p --------
__global__ void __launch_bounds__(256) k_gather_gemm(
    const int* __restrict__ adjT, const int* __restrict__ startT, const int* __restrict__ cntT,
    const _Float16* __restrict__ At, const _Float16* __restrict__ Bt,
    const float* __restrict__ Wt1, const float* __restrict__ Wt2, const float* __restrict__ bt2,
    _Float16* __restrict__ C1t, _Float16* __restrict__ C2t, int NT_,
    const int* __restrict__ adjP, const int* __restrict__ startP, const int* __restrict__ cntP,
    const _Float16* __restrict__ Ap, const _Float16* __restrict__ Bp,
    const float* __restrict__ Wp1, const float* __restrict__ Wp2, const float* __restrict__ bp2,
    _Float16* __restrict__ C1p, _Float16* __restrict__ C2p, int NP_,
    int tTB) {
    __shared__ half8v ldsW[1024];                       // 16 KiB weight fragments
    __shared__ __align__(16) _Float16 ldsC[4][2 * LDSC_TBL];  // 18 KiB per-wave C tiles
    const int tid = threadIdx.x, wave = tid >> 6;
    if ((int)blockIdx.x < tTB) {
        stage_w_lds(ldsW, Wt1, Wt2, tid);
        __syncthreads();
        int tile = blockIdx.x * 4 + wave;
        if (tile < ((NT_ + 15) >> 4))
            gather_gemm_dev(adjT, startT, cntT, At, Bt, ldsW, ldsC[wave], bt2,
                            C1t, C2t, NT_, tile);
    } else {
        stage_w_lds(ldsW, Wp1, Wp2, tid);
        __syncthreads();
        int tile = (blockIdx.x - tTB) * 4 + wave;
        if (tile < ((NP_ + 15) >> 4))
            gather_gemm_dev(adjP, startP, cntP, Ap, Bp, ldsW, ldsC[wave], bp2,
                            C1p, C2p, NP_, tile);
    }
}

// ---- gather-mean device body: 8 lanes/row, 16 loads in flight ----------
// Output is consumed RANDOMLY by dot_h -> regular cached store (keep in L2/LLC).
__device__ __forceinline__ void gather_dev(
    const int* __restrict__ adj, const int* __restrict__ start, const int* __restrict__ cnt,
    const _Float16* __restrict__ A, const _Float16* __restrict__ B,
    _Float16* __restrict__ out, int do_relu, int N, int gidx) {
    int row = gidx >> 3;
    int c   = gidx & 7;
    if (row >= N) return;

    int st = start[row];
    int dg = cnt[row];
    const half8v* A8 = (const half8v*)A;
    half8v acc = {};
    int j = 0;
    for (; j + 15 < dg; j += 16) {  // 16 gathers in flight
        int n[16];
#pragma unroll
        for (int k = 0; k < 16; ++k) n[k] = adj[st + j + k];
        half8v v[16];
#pragma unroll
        for (int k = 0; k < 16; ++k) v[k] = A8[(size_t)n[k] * 8 + c];
        half8v s0 = ((v[0] + v[1]) + (v[2] + v[3])) + ((v[4] + v[5]) + (v[6] + v[7]));
        half8v s1 = ((v[8] + v[9]) + (v[10] + v[11])) + ((v[12] + v[13]) + (v[14] + v[15]));
        acc += s0 + s1;
    }
    if (j + 7 < dg) {
        int n[8];
#pragma unroll
        for (int k = 0; k < 8; ++k) n[k] = adj[st + j + k];
        half8v v[8];
#pragma unroll
        for (int k = 0; k < 8; ++k) v[k] = A8[(size_t)n[k] * 8 + c];
        acc += ((v[0] + v[1]) + (v[2] + v[3])) + ((v[4] + v[5]) + (v[6] + v[7]));
        j += 8;
    }
    if (j + 3 < dg) {
        int n[4];
#pragma unroll
        for (int k = 0; k < 4; ++k) n[k] = adj[st + j + k];
        half8v v[4];
#pragma unroll
        for (int k = 0; k < 4; ++k) v[k] = A8[(size_t)n[k] * 8 + c];
        acc += (v[0] + v[1]) + (v[2] + v[3]);
        j += 4;
    }
    for (; j < dg; ++j)
        acc += A8[(size_t)adj[st + j] * 8 + c];

    float inv = 1.0f / (float)(dg > 1 ? dg : 1);
    half8v b8 = __builtin_nontemporal_load(&((const half8v*)B)[(size_t)row * 8 + c]);
    half8v o;
#pragma unroll
    for (int k = 0; k < 8; ++k) {
        float v = (float)acc[k] * inv + (float)b8[k];
        if (do_relu) v = fmaxf(v, 0.f);
        o[k] = (_Float16)v;
    }
    ((half8v*)out)[(size_t)row * 8 + c] = o;
}

// ---- K_E: fused [gather-t | gather-p] ----------------------------------
__global__ void __launch_bounds__(256) k_gather2(
    const int* __restrict__ adjT, const int* __restrict__ startT, const int* __restrict__ cntT,
    const _Float16* __restrict__ At, const _Float16* __restrict__ Bt, _Float16* __restrict__ outT, int NT_,
    const int* __restrict__ adjP, const int* __restrict__ startP, const int* __restrict__ cntP,
    const _Float16* __restrict__ Ap, const _Float16* __restrict__ Bp, _Float16* __restrict__ outP, int NP_,
    int do_relu, int wTb) {
    if ((int)blockIdx.x < wTb)
        gather_dev(adjT, startT, cntT, At, Bt, outT, do_relu, NT_, blockIdx.x * 256 + threadIdx.x);
    else
        gather_dev(adjP, startP, cntP, Ap, Bp, outP, do_relu, NP_,
                   (blockIdx.x - wTb) * 256 + threadIdx.x);
}

// ---- classifier: 8 lanes/edge, v_dot2_f32_f16 --------------------------
__global__ void __launch_bounds__(256) dot_h(const _Float16* __restrict__ p2,
                                             const _Float16* __restrict__ t2,
                                             const int* __restrict__ els,
                                             const int* __restrict__ eld,
                                             float* __restrict__ out, int EL) {
    int tid = blockIdx.x * 256 + threadIdx.x;
    int i = tid >> 3, c = tid & 7;
    if (i < EL) {
        int s = __builtin_nontemporal_load(&els[i]);
        int d = __builtin_nontemporal_load(&eld[i]);
        half8v a = ((const half8v*)p2)[(size_t)s * 8 + c];
        half8v b = ((const half8v*)t2)[(size_t)d * 8 + c];
        float v = 0.f;
#ifdef HAS_FDOT2
        const half2v* ap = (const half2v*)&a;
        const half2v* bp = (const half2v*)&b;
#pragma unroll
        for (int k = 0; k < 4; ++k) v = __builtin_amdgcn_fdot2(ap[k], bp[k], v, false);
#else
#pragma unroll
        for (int k = 0; k < 8; ++k) v += (float)a[k] * (float)b[k];
#endif
        v += __shfl_xor(v, 1, 64);
        v += __shfl_xor(v, 2, 64);
        v += __shfl_xor(v, 4, 64);
        if (c == 0) __builtin_nontemporal_store(v, &out[i]);
    }
}

extern "C" void kernel_launch(void* const* d_in, const int* in_sizes, int n_in,
                              void* d_out, int out_size, void* d_ws, size_t ws_size,
                              hipStream_t stream) {
    const float* x_taxon  = (const float*)d_in[0];
    const float* tlw      = (const float*)d_in[1];
    const float* tlb      = (const float*)d_in[2];
    const float* pemb     = (const float*)d_in[3];
    const float* temb     = (const float*)d_in[4];
    const int*   edge_src = (const int*)d_in[7];
    const int*   edge_dst = (const int*)d_in[8];
    const int*   el_src   = (const int*)d_in[9];
    const int*   el_dst   = (const int*)d_in[10];
    const float* c1pt_wl  = (const float*)d_in[11];
    const float* c1pt_wr  = (const float*)d_in[12];
    const float* c1tp_wl  = (const float*)d_in[13];
    const float* c1tp_wr  = (const float*)d_in[14];
    const float* c2pt_wl  = (const float*)d_in[15];
    const float* c2pt_wr  = (const float*)d_in[16];
    const float* c2tp_wl  = (const float*)d_in[17];
    const float* c2tp_wr  = (const float*)d_in[18];
    const float* c1pt_bl  = (const float*)d_in[19];
    const float* c1tp_bl  = (const float*)d_in[20];
    const float* c2pt_bl  = (const float*)d_in[21];
    const float* c2tp_bl  = (const float*)d_in[22];

    const int NP_ = in_sizes[5];
    const int NT_ = in_sizes[6];
    const int E_  = in_sizes[7];
    const int EL_ = in_sizes[9];
    const int BT  = (NT_ + ST - 1) / ST;   // 391
    const int BP  = (NP_ + SP - 1) / SP;   // 391

    // workspace (same 4*NT + 4*NP f16-row footprint as before):
    //   XTh  [NT]: K_A out, K_B in; then Aht2 alias (K_CD out, K_E in)
    //   Aht1 [NT]: K_B out, K_CD p-gather table; then T2h alias (K_E out)
    //   Bth1 [NT]: K_B out, K_CD t-addend
    //   Bth2 [NT]: K_CD out, K_E t-addend
    //   Ahp1 [NP]: K_B out, K_CD t-gather table; then P2h alias (K_E out)
    //   Bph1 [NP]: K_B out, K_CD p-addend
    //   Ahp2 [NP]: K_CD out, K_E t-gather table
    //   Bph2 [NP]: K_CD out, K_E p-addend
    _Float16* hb   = (_Float16*)d_ws;
    _Float16* XTh  = hb;
    _Float16* Aht1 = XTh + (size_t)NT_ * H;
    _Float16* Bth1 = Aht1 + (size_t)NT_ * H;
    _Float16* Bth2 = Bth1 + (size_t)NT_ * H;
    _Float16* Ahp1 = Bth2 + (size_t)NT_ * H;
    _Float16* Bph1 = Ahp1 + (size_t)NP_ * H;
    _Float16* Ahp2 = Bph1 + (size_t)NP_ * H;
    _Float16* Bph2 = Ahp2 + (size_t)NP_ * H;
    _Float16* Aht2 = XTh;    // alias: XTh dead after K_B
    _Float16* T2h  = Aht1;   // alias: Aht1 dead after K_CD
    _Float16* P2h  = Ahp1;   // alias: Ahp1 dead after K_CD

    unsigned* binT    = (unsigned*)(Bph2 + (size_t)NP_ * H);  // BT*CAPB
    unsigned* binP    = binT + (size_t)BT * CAPB;             // BP*CAPB
    int*      adj_t   = (int*)(binP + (size_t)BP * CAPB);     // BT*CAPB
    int*      adj_p   = adj_t + (size_t)BT * CAPB;            // BP*CAPB
    int* start_t = adj_p + (size_t)BP * CAPB;  // NT
    int* start_p = start_t + NT_;              // NP
    int* cnt_t   = start_p + NP_;              // NT
    int* cnt_p   = cnt_t + NT_;                // NP
    int* curT    = cnt_p + NP_;                // BMAX
    int* curP    = curT + BMAX;                // BMAX

    (void)hipMemsetAsync(curT, 0, 2 * BMAX * sizeof(int), stream);

    const int nbBin = (E_ + EPB - 1) / EPB;              // 489
    const int XTB   = 512;                               // xt GEMM blocks
    const int wT = (NT_ * 8 + 255) / 256, wP = (NP_ * 8 + 255) / 256;
    const int tB = 256, pB = 512;                        // MFMA pair split (tiles 1:2)

    // K_A: bin (blocks 0..nbBin, dispatched first => owns the CUs early) + xt GEMM
    k_bin_xt<<<nbBin + XTB, 256, 0, stream>>>(
        edge_src, edge_dst, curT, curP, binT, binP, BT, BP, E_, nbBin,
        x_taxon, tlw, tlb, temb, XTh, NT_, XTB);

    // K_B: csr-t + csr-p + layer-1 MFMA pair
    //   Aht1 = XT@c1tp_wl, Bth1 = XT@c1pt_wr + c1pt_bl
    //   Ahp1 = pemb@c1pt_wl, Bph1 = pemb@c1tp_wr + c1tp_bl
    k_csr_mfma1<<<BT + BP + tB + pB, 256, 0, stream>>>(
        binT, binP, curT, curP,
        start_t, cnt_t, adj_t, start_p, cnt_p, adj_p, BT, BP, NT_, NP_,
        XTh, c1tp_wl, c1pt_wr, c1pt_bl, Aht1, Bth1,
        pemb, c1pt_wl, c1tp_wr, c1tp_bl, Ahp1, Bph1, tB, pB);

    // K_CD: fused layer-1 gather (+relu) + layer-2 dual GEMM
    //   t: t1 = relu(mean(Ahp1)+Bth1); Aht2 = t1@c2tp_wl; Bth2 = t1@c2pt_wr + c2pt_bl
    //   p: p1 = relu(mean(Aht1)+Bph1); Ahp2 = p1@c2pt_wl; Bph2 = p1@c2tp_wr + c2tp_bl
    const int tTB = (((NT_ + 15) >> 4) + 3) >> 2;
    const int pTB = (((NP_ + 15) >> 4) + 3) >> 2;
    k_gather_gemm<<<tTB + pTB, 256, 0, stream>>>(
        adj_t, start_t, cnt_t, Ahp1, Bth1, c2tp_wl, c2pt_wr, c2pt_bl, Aht2, Bth2, NT_,
        adj_p, start_p, cnt_p, Aht1, Bph1, c2pt_wl, c2tp_wr, c2tp_bl, Ahp2, Bph2, NP_,
        tTB);

    // K_E: layer-2 gathers (no relu)
    //   t2 = mean(Ahp2)+Bth2 -> T2h ; p2 = mean(Aht2)+Bph2 -> P2h
    k_gather2<<<wT + wP, 256, 0, stream>>>(
        adj_t, start_t, cnt_t, Ahp2, Bth2, T2h, NT_,
        adj_p, start_p, cnt_p, Aht2, Bph2, P2h, NP_, 0, wT);

    // classifier
    dot_h<<<(EL_ * 8 + 255) / 256, 256, 0, stream>>>(P2h, T2h, el_src, el_dst,
                                                     (float*)d_out, EL_);
}

// Round 8
// 446.697 us; speedup vs baseline: 1.1301x; 1.0304x over previous
//
#include <hip/hip_runtime.h>

#define H 64
#define EPB 4096        // edges per bin block (489 blocks)
#define BMAX 400        // >= bucket count (391)
#define ST 256          // taxon rows per bucket
#define SP 512          // palmprint rows per bucket
#define LSHT 18         // t-entry: (dst&255)<<18 | src
#define LSHP 17         // p-entry: (src&511)<<17 | dst
#define CAPB 5632       // bucket capacity (mean 5120 + 7 sigma); %4==0

typedef _Float16 half2v __attribute__((ext_vector_type(2)));
typedef _Float16 half8v __attribute__((ext_vector_type(8)));
typedef _Float16 f16x8  __attribute__((ext_vector_type(8)));
typedef float    f32x4  __attribute__((ext_vector_type(4)));
typedef int      i32x4  __attribute__((ext_vector_type(4)));

#if defined(__has_builtin)
#if __has_builtin(__builtin_amdgcn_fdot2)
#define HAS_FDOT2 1
#endif
#endif

#define MFMA16(a, b, c) __builtin_amdgcn_mfma_f32_16x16x32_f16(a, b, c, 0, 0, 0)

// ---- MFMA xt device body: C = A(f32)@W + bias + addend(f32), f16 out ----
__device__ __forceinline__ void mfma_xt_dev(const float* __restrict__ A,
                                            const float* __restrict__ W,
                                            const float* __restrict__ bias,
                                            const float* __restrict__ addend,
                                            _Float16* __restrict__ C,
                                            int N, int wid, int nwaves) {
    const int lane = threadIdx.x & 63;
    const int m = lane & 15, quad = lane >> 4;
    const int nTiles = (N + 15) >> 4;

    f16x8 wf[2][4];
#pragma unroll
    for (int kh = 0; kh < 2; ++kh)
#pragma unroll
        for (int nt = 0; nt < 4; ++nt) {
            f16x8 a;
#pragma unroll
            for (int j = 0; j < 8; ++j) {
                int k = kh * 32 + quad * 8 + j;
                a[j] = (_Float16)W[k * 64 + nt * 16 + m];
            }
            wf[kh][nt] = a;
        }
    float bv[4];
#pragma unroll
    for (int nt = 0; nt < 4; ++nt) bv[nt] = bias[nt * 16 + m];

    for (int t = wid; t < nTiles; t += nwaves) {
        int row = t * 16 + m;
        f16x8 alo = {}, ahi = {};
        if (row < N) {
            const f32x4* p = (const f32x4*)(A + (size_t)row * 64);
            f32x4 x0 = __builtin_nontemporal_load(p + quad * 2);
            f32x4 x1 = __builtin_nontemporal_load(p + quad * 2 + 1);
            f32x4 x2 = __builtin_nontemporal_load(p + 8 + quad * 2);
            f32x4 x3 = __builtin_nontemporal_load(p + 8 + quad * 2 + 1);
            alo[0] = (_Float16)x0[0]; alo[1] = (_Float16)x0[1];
            alo[2] = (_Float16)x0[2]; alo[3] = (_Float16)x0[3];
            alo[4] = (_Float16)x1[0]; alo[5] = (_Float16)x1[1];
            alo[6] = (_Float16)x1[2]; alo[7] = (_Float16)x1[3];
            ahi[0] = (_Float16)x2[0]; ahi[1] = (_Float16)x2[1];
            ahi[2] = (_Float16)x2[2]; ahi[3] = (_Float16)x2[3];
            ahi[4] = (_Float16)x3[0]; ahi[5] = (_Float16)x3[1];
            ahi[6] = (_Float16)x3[2]; ahi[7] = (_Float16)x3[3];
        }
#pragma unroll
        for (int nt = 0; nt < 4; ++nt) {
            f32x4 a1 = {0.f, 0.f, 0.f, 0.f};
            a1 = MFMA16(alo, wf[0][nt], a1);
            a1 = MFMA16(ahi, wf[1][nt], a1);
#pragma unroll
            for (int r = 0; r < 4; ++r) {
                int orow = t * 16 + quad * 4 + r;
                if (orow < N) {
                    float ad = __builtin_nontemporal_load(
                        &addend[(size_t)orow * 64 + nt * 16 + m]);
                    C[(size_t)orow * 64 + nt * 16 + m] = (_Float16)(a1[r] + bv[nt] + ad);
                }
            }
        }
    }
}

// in-place inclusive scan over sc[0..511] (counts pre-loaded), 256 threads
__device__ __forceinline__ void block_scan512(int* sc, int tid) {
    for (int off = 1; off < 512; off <<= 1) {
        int i0 = tid, i1 = tid + 256;
        int v0 = (i0 >= off) ? sc[i0 - off] : 0;
        int v1 = (i1 >= off) ? sc[i1 - off] : 0;
        __syncthreads();
        sc[i0] += v0;
        sc[i1] += v1;
        __syncthreads();
    }
}

// ---- K_A: fused [bin (LDS sort-then-stream) | xt GEMM | pemb cast] -----
__global__ void __launch_bounds__(256) k_bin_xt(
    const int* __restrict__ src, const int* __restrict__ dst,
    int* __restrict__ curT, int* __restrict__ curP,
    unsigned* __restrict__ binT, unsigned* __restrict__ binP,
    int BT, int BP, int E, int nbBin,
    const float* __restrict__ A, const float* __restrict__ W,
    const float* __restrict__ bias, const float* __restrict__ addend,
    _Float16* __restrict__ C, int NT_, int xtBlocks,
    const float* __restrict__ pembIn, _Float16* __restrict__ PhOut,
    int NP_, int castBlocks) {
    __shared__ int cT[BMAX], cP[BMAX], oT[BMAX], oP[BMAX], cur[BMAX];
    __shared__ int sc[512];
    __shared__ unsigned stage[EPB];
    int tid = threadIdx.x;
    if ((int)blockIdx.x >= nbBin + xtBlocks) {
        // pemb f32 -> f16 cast (read-once stream)
        int cb = blockIdx.x - nbBin - xtBlocks;
        int idx = cb * 256 + tid, stride = castBlocks * 256;
        int total = NP_ * 8;
        for (int i = idx; i < total; i += stride) {
            const f32x4* p = (const f32x4*)(pembIn + (size_t)i * 8);
            f32x4 x0 = __builtin_nontemporal_load(p);
            f32x4 x1 = __builtin_nontemporal_load(p + 1);
            f16x8 o;
            o[0] = (_Float16)x0[0]; o[1] = (_Float16)x0[1];
            o[2] = (_Float16)x0[2]; o[3] = (_Float16)x0[3];
            o[4] = (_Float16)x1[0]; o[5] = (_Float16)x1[1];
            o[6] = (_Float16)x1[2]; o[7] = (_Float16)x1[3];
            *(f16x8*)&PhOut[(size_t)i * 8] = o;
        }
        return;
    }
    if ((int)blockIdx.x >= nbBin) {
        int xb = blockIdx.x - nbBin;
        mfma_xt_dev(A, W, bias, addend, C, NT_, xb * 4 + (tid >> 6), xtBlocks * 4);
        return;
    }
    const int wave = tid >> 6, lane = tid & 63;
    for (int i = tid; i < BMAX; i += 256) { cT[i] = 0; cP[i] = 0; }
    __syncthreads();
    int e0 = blockIdx.x * EPB;
    int ls[EPB / 256], ld[EPB / 256];
#pragma unroll
    for (int k = 0; k < EPB / 256; ++k) {
        int i = e0 + k * 256 + tid;
        if (i < E) {
            ls[k] = __builtin_nontemporal_load(&src[i]);
            ld[k] = __builtin_nontemporal_load(&dst[i]);
            atomicAdd(&cT[ld[k] >> 8], 1);
            atomicAdd(&cP[ls[k] >> 9], 1);
        }
    }
    __syncthreads();
    // grab global chunks
    for (int b = tid; b < BT; b += 256) { int c = cT[b]; oT[b] = c ? atomicAdd(&curT[b], c) : 0; }
    for (int b = tid; b < BP; b += 256) { int c = cP[b]; oP[b] = c ? atomicAdd(&curP[b], c) : 0; }
    // ---- T side: scan, scatter to LDS, stream out ----
    sc[tid]       = (tid < BT) ? cT[tid] : 0;
    sc[tid + 256] = (tid + 256 < BT) ? cT[tid + 256] : 0;
    __syncthreads();
    block_scan512(sc, tid);
    for (int b = tid; b < BT; b += 256) cur[b] = sc[b] - cT[b];
    __syncthreads();
#pragma unroll
    for (int k = 0; k < EPB / 256; ++k) {
        int i = e0 + k * 256 + tid;
        if (i < E) {
            int bt = ld[k] >> 8;
            int pos = atomicAdd(&cur[bt], 1);
            stage[pos] = ((unsigned)(ld[k] & 255) << LSHT) | (unsigned)ls[k];
        }
    }
    __syncthreads();
    for (int b = wave; b < BT; b += 4) {
        int cnt = cT[b], so = sc[b] - cnt, go = oT[b];
        for (int i = lane; i < cnt; i += 64) {
            int pos = go + i;
            if (pos < CAPB) binT[(size_t)b * CAPB + pos] = stage[so + i];
        }
    }
    __syncthreads();
    // ---- P side ----
    sc[tid]       = (tid < BP) ? cP[tid] : 0;
    sc[tid + 256] = (tid + 256 < BP) ? cP[tid + 256] : 0;
    __syncthreads();
    block_scan512(sc, tid);
    for (int b = tid; b < BP; b += 256) cur[b] = sc[b] - cP[b];
    __syncthreads();
#pragma unroll
    for (int k = 0; k < EPB / 256; ++k) {
        int i = e0 + k * 256 + tid;
        if (i < E) {
            int bp = ls[k] >> 9;
            int pos = atomicAdd(&cur[bp], 1);
            stage[pos] = ((unsigned)(ls[k] & 511) << LSHP) | (unsigned)ld[k];
        }
    }
    __syncthreads();
    for (int b = wave; b < BP; b += 4) {
        int cnt = cP[b], so = sc[b] - cnt, go = oP[b];
        for (int i = lane; i < cnt; i += 64) {
            int pos = go + i;
            if (pos < CAPB) binP[(size_t)b * CAPB + pos] = stage[so + i];
        }
    }
}

// ---- CSR per-bucket device body: scatter into LDS, stream out int4 -----
__device__ __forceinline__ void csr_dev(const unsigned* __restrict__ binned,
                                        const int* __restrict__ cur,
                                        int* __restrict__ start_g, int* __restrict__ cnt_g,
                                        int* __restrict__ adj,
                                        int S, int lshift, int N, int b,
                                        int* lcnt, int* lscan, int* lcur, int* adj_lds) {
    int tid = threadIdx.x;
    int base = b * CAPB;
    int n = cur[b]; if (n > CAPB) n = CAPB;
    int rowlo = b * S;
    unsigned nbmask = (1u << lshift) - 1u;

    for (int i = tid; i < S; i += 256) lcnt[i] = 0;
    __syncthreads();
    for (int i = tid; i < n; i += 256)
        atomicAdd(&lcnt[binned[base + i] >> lshift], 1);
    __syncthreads();
    for (int i = tid; i < S; i += 256) lscan[i] = lcnt[i];
    __syncthreads();
    for (int off = 1; off < S; off <<= 1) {
        int i0 = tid, i1 = tid + 256;
        int v0 = (i0 >= off) ? lscan[i0 - off] : 0;
        int v1 = (S > 256 && i1 >= off) ? lscan[i1 - off] : 0;
        __syncthreads();
        if (i0 < S) lscan[i0] += v0;
        if (S > 256 && i1 < S) lscan[i1] += v1;
        __syncthreads();
    }
    for (int r = tid; r < S; r += 256) {
        int ex = lscan[r] - lcnt[r];
        lcur[r] = ex;
        int row = rowlo + r;
        if (row < N) {
            start_g[row] = base + ex;
            cnt_g[row]   = lcnt[r];
        }
    }
    __syncthreads();
    for (int i = tid; i < n; i += 256) {
        unsigned e = binned[base + i];
        int r = e >> lshift;
        int pos = atomicAdd(&lcur[r], 1);
        adj_lds[pos] = (int)(e & nbmask);
    }
    __syncthreads();
    int n4 = n & ~3;
    for (int i = tid * 4; i < n4; i += 1024)
        *(int4*)&adj[base + i] = *(const int4*)&adj_lds[i];
    for (int i = n4 + tid; i < n; i += 256)
        adj[base + i] = adj_lds[i];
}

// ---- K_B: [csr-t | csr-p] ----------------------------------------------
__global__ void __launch_bounds__(256) k_csr(
    const unsigned* __restrict__ binT, const unsigned* __restrict__ binP,
    const int* __restrict__ curT, const int* __restrict__ curP,
    int* __restrict__ start_t, int* __restrict__ cnt_t, int* __restrict__ adj_t,
    int* __restrict__ start_p, int* __restrict__ cnt_p, int* __restrict__ adj_p,
    int BT, int BP, int NT_, int NP_) {
    __shared__ int lcnt[512], lscan[512], lcur[512];
    __shared__ int adj_lds[CAPB];
    int bi = blockIdx.x;
    if (bi < BT)
        csr_dev(binT, curT, start_t, cnt_t, adj_t, ST, LSHT, NT_, bi, lcnt, lscan, lcur, adj_lds);
    else
        csr_dev(binP, curP, start_p, cnt_p, adj_p, SP, LSHP, NP_, bi - BT, lcnt, lscan, lcur, adj_lds);
}

// ---- weight staging: pre-swizzled per-lane MFMA B-fragments into LDS ----
// layout: frag[(tbl*8 + kh*4 + nt)*64 + lane]; tbl0 = Wl, tbl1 = Wr
__device__ __forceinline__ void stage_w_lds(half8v* ldsW,
                                            const float* __restrict__ W1,
                                            const float* __restrict__ W2, int tid) {
    for (int f = tid; f < 1024; f += 256) {
        int lane = f & 63, nt = (f >> 6) & 3, kh = (f >> 8) & 1, tbl = f >> 9;
        int m = lane & 15, quad = lane >> 4;
        const float* W = tbl ? W2 : W1;
        half8v frag;
#pragma unroll
        for (int j = 0; j < 8; ++j) {
            int k = kh * 32 + quad * 8 + j;
            frag[j] = (_Float16)W[k * 64 + nt * 16 + m];
        }
        ldsW[f] = frag;
    }
}

// ---- fused gather-mean + dual-weight GEMM (mean@Wl + Self@Wr + b) ------
// Gather raw feature rows G[nb] in MFMA A-fragment layout, mean, then
// out = mean@Wl + Self[row]@Wr + b (optional relu), LDS-coalesced store.
#define LDSC_STRIDE 72   // halves per row (144 B)
#define LDSC_TBL    1152 // halves per wave tile (16 rows)
__device__ __forceinline__ void gg_dev(
    const int* __restrict__ adj, const int* __restrict__ start, const int* __restrict__ cnt,
    const _Float16* __restrict__ G, const _Float16* __restrict__ S,
    const half8v* __restrict__ ldsW, _Float16* __restrict__ ldsC_w,
    const float* __restrict__ bias,
    _Float16* __restrict__ out, int N, int tile, int do_relu) {
    const int lane = threadIdx.x & 63;
    const int m = lane & 15, quad = lane >> 4;
    const int row = tile * 16 + m;

    half8v accl = {}, acch = {};
    int dg = 0;
    if (row < N) {
        int st = start[row];
        dg     = cnt[row];
        const half8v* G8 = (const half8v*)G;
        int j = 0;
        for (; j + 7 < dg; j += 8) {   // 8 neighbors x 2 chunks in flight
            int n[8];
#pragma unroll
            for (int k = 0; k < 8; ++k) n[k] = adj[st + j + k];
            half8v lv[8], hv[8];
#pragma unroll
            for (int k = 0; k < 8; ++k) {
                const half8v* rp = G8 + (size_t)n[k] * 8 + quad;
                lv[k] = rp[0];
                hv[k] = rp[4];
            }
            accl += ((lv[0] + lv[1]) + (lv[2] + lv[3])) + ((lv[4] + lv[5]) + (lv[6] + lv[7]));
            acch += ((hv[0] + hv[1]) + (hv[2] + hv[3])) + ((hv[4] + hv[5]) + (hv[6] + hv[7]));
        }
        if (j + 3 < dg) {
            int n[4];
#pragma unroll
            for (int k = 0; k < 4; ++k) n[k] = adj[st + j + k];
            half8v lv[4], hv[4];
#pragma unroll
            for (int k = 0; k < 4; ++k) {
                const half8v* rp = G8 + (size_t)n[k] * 8 + quad;
                lv[k] = rp[0];
                hv[k] = rp[4];
            }
            accl += (lv[0] + lv[1]) + (lv[2] + lv[3]);
            acch += (hv[0] + hv[1]) + (hv[2] + hv[3]);
            j += 4;
        }
        for (; j < dg; ++j) {
            const half8v* rp = G8 + (size_t)adj[st + j] * 8 + quad;
            accl += rp[0];
            acch += rp[4];
        }
    }

    f16x8 alo = {}, ahi = {}, slo = {}, shi = {};
    if (row < N) {
        float inv = 1.0f / (float)(dg > 1 ? dg : 1);
#pragma unroll
        for (int k = 0; k < 8; ++k) {
            alo[k] = (_Float16)((float)accl[k] * inv);
            ahi[k] = (_Float16)((float)acch[k] * inv);
        }
        const f16x8* S8 = (const f16x8*)S;
        slo = S8[(size_t)row * 8 + quad];       // self rows: hot gather table for
        shi = S8[(size_t)row * 8 + 4 + quad];   // the other side -> keep cached
    }

#pragma unroll
    for (int nt = 0; nt < 4; ++nt) {
        f16x8 wl_lo = (f16x8)ldsW[(0 * 8 + 0 * 4 + nt) * 64 + lane];
        f16x8 wl_hi = (f16x8)ldsW[(0 * 8 + 1 * 4 + nt) * 64 + lane];
        f16x8 wr_lo = (f16x8)ldsW[(1 * 8 + 0 * 4 + nt) * 64 + lane];
        f16x8 wr_hi = (f16x8)ldsW[(1 * 8 + 1 * 4 + nt) * 64 + lane];
        f32x4 a = {0.f, 0.f, 0.f, 0.f};
        a = MFMA16(alo, wl_lo, a);
        a = MFMA16(ahi, wl_hi, a);
        a = MFMA16(slo, wr_lo, a);
        a = MFMA16(shi, wr_hi, a);
        float bb = bias[nt * 16 + m];
#pragma unroll
        for (int r = 0; r < 4; ++r) {
            float v = a[r] + bb;
            if (do_relu) v = fmaxf(v, 0.f);
            ldsC_w[(quad * 4 + r) * LDSC_STRIDE + nt * 16 + m] = (_Float16)v;
        }
    }

    // coalesced store: lane -> (row = lane>>2, 16B chunk = lane&3), 2 halves
    {
        int rl = lane >> 2, ch = lane & 3;
        int orow = tile * 16 + rl;
        if (orow < N) {
#pragma unroll
            for (int half = 0; half < 2; ++half) {
                int lo = rl * LDSC_STRIDE + ch * 8 + half * 32;
                f16x8 v = *(const f16x8*)&ldsC_w[lo];
                *(f16x8*)&out[(size_t)orow * 64 + ch * 8 + half * 32] = v;
            }
        }
    }
}

// ---- K_C/K_D: fused [gather+dual GEMM], t | p --------------------------
__global__ void __launch_bounds__(256) k_gg(
    const int* __restrict__ adjT, const int* __restrict__ startT, const int* __restrict__ cntT,
    const _Float16* __restrict__ Gt, const _Float16* __restrict__ St,
    const float* __restrict__ Wlt, const float* __restrict__ Wrt, const float* __restrict__ bt,
    _Float16* __restrict__ outT, int NT_,
    const int* __restrict__ adjP, const int* __restrict__ startP, const int* __restrict__ cntP,
    const _Float16* __restrict__ Gp, const _Float16* __restrict__ Sp,
    const float* __restrict__ Wlp, const float* __restrict__ Wrp, const float* __restrict__ bp,
    _Float16* __restrict__ outP, int NP_,
    int tTB, int do_relu) {
    __shared__ half8v ldsW[1024];                            // 16 KiB weight fragments
    __shared__ __align__(16) _Float16 ldsC[4][LDSC_TBL];     // 9 KiB per-wave C tiles
    const int tid = threadIdx.x, wave = tid >> 6;
    if ((int)blockIdx.x < tTB) {
        stage_w_lds(ldsW, Wlt, Wrt, tid);
        __syncthreads();
        int tile = blockIdx.x * 4 + wave;
        if (tile < ((NT_ + 15) >> 4))
            gg_dev(adjT, startT, cntT, Gt, St, ldsW, ldsC[wave], bt, outT, NT_, tile, do_relu);
    } else {
        stage_w_lds(ldsW, Wlp, Wrp, tid);
        __syncthreads();
        int tile = (blockIdx.x - tTB) * 4 + wave;
        if (tile < ((NP_ + 15) >> 4))
            gg_dev(adjP, startP, cntP, Gp, Sp, ldsW, ldsC[wave], bp, outP, NP_, tile, do_relu);
    }
}

// ---- classifier: 8 lanes/edge, v_dot2_f32_f16 --------------------------
__global__ void __launch_bounds__(256) dot_h(const _Float16* __restrict__ p2,
                                             const _Float16* __restrict__ t2,
                                             const int* __restrict__ els,
                                             const int* __restrict__ eld,
                                             float* __restrict__ out, int EL) {
    int tid = blockIdx.x * 256 + threadIdx.x;
    int i = tid >> 3, c = tid & 7;
    if (i < EL) {
        int s = __builtin_nontemporal_load(&els[i]);
        int d = __builtin_nontemporal_load(&eld[i]);
        half8v a = ((const half8v*)p2)[(size_t)s * 8 + c];
        half8v b = ((const half8v*)t2)[(size_t)d * 8 + c];
        float v = 0.f;
#ifdef HAS_FDOT2
        const half2v* ap = (const half2v*)&a;
        const half2v* bp = (const half2v*)&b;
#pragma unroll
        for (int k = 0; k < 4; ++k) v = __builtin_amdgcn_fdot2(ap[k], bp[k], v, false);
#else
#pragma unroll
        for (int k = 0; k < 8; ++k) v += (float)a[k] * (float)b[k];
#endif
        v += __shfl_xor(v, 1, 64);
        v += __shfl_xor(v, 2, 64);
        v += __shfl_xor(v, 4, 64);
        if (c == 0) __builtin_nontemporal_store(v, &out[i]);
    }
}

extern "C" void kernel_launch(void* const* d_in, const int* in_sizes, int n_in,
                              void* d_out, int out_size, void* d_ws, size_t ws_size,
                              hipStream_t stream) {
    const float* x_taxon  = (const float*)d_in[0];
    const float* tlw      = (const float*)d_in[1];
    const float* tlb      = (const float*)d_in[2];
    const float* pemb     = (const float*)d_in[3];
    const float* temb     = (const float*)d_in[4];
    const int*   edge_src = (const int*)d_in[7];
    const int*   edge_dst = (const int*)d_in[8];
    const int*   el_src   = (const int*)d_in[9];
    const int*   el_dst   = (const int*)d_in[10];
    const float* c1pt_wl  = (const float*)d_in[11];
    const float* c1pt_wr  = (const float*)d_in[12];
    const float* c1tp_wl  = (const float*)d_in[13];
    const float* c1tp_wr  = (const float*)d_in[14];
    const float* c2pt_wl  = (const float*)d_in[15];
    const float* c2pt_wr  = (const float*)d_in[16];
    const float* c2tp_wl  = (const float*)d_in[17];
    const float* c2tp_wr  = (const float*)d_in[18];
    const float* c1pt_bl  = (const float*)d_in[19];
    const float* c1tp_bl  = (const float*)d_in[20];
    const float* c2pt_bl  = (const float*)d_in[21];
    const float* c2tp_bl  = (const float*)d_in[22];

    const int NP_ = in_sizes[5];
    const int NT_ = in_sizes[6];
    const int E_  = in_sizes[7];
    const int EL_ = in_sizes[9];
    const int BT  = (NT_ + ST - 1) / ST;   // 391
    const int BP  = (NP_ + SP - 1) / SP;   // 391

    // workspace (gather-then-transform: only raw feature tables live):
    //   XTh [NT]: K_A out (x@tlw+tlb+temb); L1-p gather table, L1-t self; t2 alias
    //   Ph  [NP]: K_A out (f16 pemb);       L1-t gather table, L1-p self; p2 alias
    //   t1  [NT]: L1 out; L2-p gather table, L2-t self
    //   p1  [NP]: L1 out; L2-t gather table, L2-p self
    _Float16* hb  = (_Float16*)d_ws;
    _Float16* XTh = hb;
    _Float16* Ph  = XTh + (size_t)NT_ * H;
    _Float16* t1  = Ph + (size_t)NP_ * H;
    _Float16* p1  = t1 + (size_t)NT_ * H;
    _Float16* t2  = XTh;   // alias: XTh dead after L1
    _Float16* p2  = Ph;    // alias: Ph dead after L1

    unsigned* binT    = (unsigned*)(p1 + (size_t)NP_ * H);   // BT*CAPB
    unsigned* binP    = binT + (size_t)BT * CAPB;            // BP*CAPB
    int*      adj_t   = (int*)(binP + (size_t)BP * CAPB);    // BT*CAPB
    int*      adj_p   = adj_t + (size_t)BT * CAPB;           // BP*CAPB
    int* start_t = adj_p + (size_t)BP * CAPB;  // NT
    int* start_p = start_t + NT_;              // NP
    int* cnt_t   = start_p + NP_;              // NT
    int* cnt_p   = cnt_t + NT_;                // NP
    int* curT    = cnt_p + NP_;                // BMAX
    int* curP    = curT + BMAX;                // BMAX

    (void)hipMemsetAsync(curT, 0, 2 * BMAX * sizeof(int), stream);

    const int nbBin = (E_ + EPB - 1) / EPB;              // 489
    const int XTB   = 512;                               // xt GEMM blocks
    const int CASTB = 256;                               // pemb cast blocks

    // K_A: bin + xt GEMM (XTh = x_taxon@tlw + tlb + temb) + pemb->f16 cast
    k_bin_xt<<<nbBin + XTB + CASTB, 256, 0, stream>>>(
        edge_src, edge_dst, curT, curP, binT, binP, BT, BP, E_, nbBin,
        x_taxon, tlw, tlb, temb, XTh, NT_, XTB, pemb, Ph, NP_, CASTB);

    // K_B: csr-t + csr-p (no GEMMs — tables eliminated by mean/linear commute)
    k_csr<<<BT + BP, 256, 0, stream>>>(
        binT, binP, curT, curP,
        start_t, cnt_t, adj_t, start_p, cnt_p, adj_p, BT, BP, NT_, NP_);

    const int tTB = (((NT_ + 15) >> 4) + 3) >> 2;
    const int pTB = (((NP_ + 15) >> 4) + 3) >> 2;

    // L1: t1 = relu(mean(Ph[src])@c1pt_wl + XTh@c1pt_wr + c1pt_bl)
    //     p1 = relu(mean(XTh[dst])@c1tp_wl + Ph@c1tp_wr + c1tp_bl)
    k_gg<<<tTB + pTB, 256, 0, stream>>>(
        adj_t, start_t, cnt_t, Ph, XTh, c1pt_wl, c1pt_wr, c1pt_bl, t1, NT_,
        adj_p, start_p, cnt_p, XTh, Ph, c1tp_wl, c1tp_wr, c1tp_bl, p1, NP_,
        tTB, 1);

    // L2: t2 = mean(p1[src])@c2pt_wl + t1@c2pt_wr + c2pt_bl
    //     p2 = mean(t1[dst])@c2tp_wl + p1@c2tp_wr + c2tp_bl
    k_gg<<<tTB + pTB, 256, 0, stream>>>(
        adj_t, start_t, cnt_t, p1, t1, c2pt_wl, c2pt_wr, c2pt_bl, t2, NT_,
        adj_p, start_p, cnt_p, t1, p1, c2tp_wl, c2tp_wr, c2tp_bl, p2, NP_,
        tTB, 0);

    // classifier
    dot_h<<<(EL_ * 8 + 255) / 256, 256, 0, stream>>>(p2, t2, el_src, el_dst,
                                                     (float*)d_out, EL_);
}